// Round 11
// baseline (904.720 us; speedup 1.0000x reference)
//
#include <hip/hip_runtime.h>
#include <math.h>

#define NN 50000
#define NE 800000

typedef __attribute__((ext_vector_type(8))) unsigned short us8;
typedef __attribute__((ext_vector_type(8))) __bf16 bf8;
typedef __attribute__((ext_vector_type(4))) float f4;

__device__ __forceinline__ unsigned short f2bf(float f) {
  unsigned int u = __float_as_uint(f);
  unsigned int r = u + 0x7FFFu + ((u >> 16) & 1u);
  return (unsigned short)(r >> 16);
}
__device__ __forceinline__ float bf2f(unsigned short h) {
  return __uint_as_float(((unsigned int)h) << 16);
}
__device__ __forceinline__ f4 mfma16(us8 a, us8 b, f4 c) {
  return __builtin_amdgcn_mfma_f32_16x16x32_bf16(
      __builtin_bit_cast(bf8, a), __builtin_bit_cast(bf8, b), c, 0, 0, 0);
}
__device__ __forceinline__ uint2 pack4(float a, float b, float c, float d) {
  uint2 r;
  r.x = (unsigned)f2bf(a) | ((unsigned)f2bf(b) << 16);
  r.y = (unsigned)f2bf(c) | ((unsigned)f2bf(d) << 16);
  return r;
}

// ---------------------------------------------------------------------------
// BN stats pass 1: per-block partial sums (NO atomics). blocks [0,256) = x,
// [256,1280) = ea. Writes pstat[b][0:64]=sum, pstat[b][64:128]=sumsq.
__global__ void prep_stats(const float* __restrict__ x, const float* __restrict__ ea,
                           float* __restrict__ pstat) {
  int b = blockIdx.x;
  int t = threadIdx.x;
  const float* srcp; int rows; int nblk, b0;
  if (b < 256) { srcp = x;  rows = NN; nblk = 256;  b0 = b; }
  else         { srcp = ea; rows = NE; nblk = 1024; b0 = b - 256; }
  int cg = (t & 15) * 4;           // column group (4 cols)
  int rs = t >> 4;                 // row slot 0..15
  float4 s = {0.f, 0.f, 0.f, 0.f}, q = {0.f, 0.f, 0.f, 0.f};
  for (int r = b0 * 64 + rs; r < rows; r += nblk * 64) {
    #pragma unroll
    for (int u = 0; u < 4; ++u) {
      int rr = r + u * 16;
      if (rr < rows) {
        float4 v = *(const float4*)(srcp + (size_t)rr * 64 + cg);
        s.x += v.x; s.y += v.y; s.z += v.z; s.w += v.w;
        q.x += v.x * v.x; q.y += v.y * v.y; q.z += v.z * v.z; q.w += v.w * v.w;
      }
    }
  }
  __shared__ float4 ls[256], lq[256];
  ls[t] = s; lq[t] = q;
  __syncthreads();
  if (rs == 0) {
    #pragma unroll
    for (int i = 1; i < 16; ++i) {
      float4 a = ls[i * 16 + t], z = lq[i * 16 + t];
      s.x += a.x; s.y += a.y; s.z += a.z; s.w += a.w;
      q.x += z.x; q.y += z.y; q.z += z.z; q.w += z.w;
    }
    *(float4*)&pstat[(size_t)b * 128 + cg] = s;
    *(float4*)&pstat[(size_t)b * 128 + 64 + cg] = q;
  }
}

// BN stats pass 2: reduce partials -> scale/bias. block 0 = x, block 1 = ea.
__global__ void reduce_stats(const float* __restrict__ pstat,
                             const float* __restrict__ gh_w, const float* __restrict__ gh_b,
                             const float* __restrict__ gv_w, const float* __restrict__ gv_b,
                             float* __restrict__ sb) {
  int t = threadIdx.x;             // 1024
  int col = t & 63, slot = t >> 6; // 16 slots
  int base = blockIdx.x ? 256 : 0;
  int n = blockIdx.x ? 1024 : 256;
  float s = 0.f, q = 0.f;
  for (int r = slot; r < n; r += 16) {
    s += pstat[(size_t)(base + r) * 128 + col];
    q += pstat[(size_t)(base + r) * 128 + 64 + col];
  }
  __shared__ float ls[1024], lq[1024];
  ls[t] = s; lq[t] = q;
  __syncthreads();
  if (slot == 0) {
    #pragma unroll
    for (int i = 1; i < 16; ++i) { s += ls[i * 64 + col]; q += lq[i * 64 + col]; }
    float inv = blockIdx.x ? (1.0f / NE) : (1.0f / NN);
    const float* gp = blockIdx.x ? gv_w : gh_w;
    const float* bp = blockIdx.x ? gv_b : gh_b;
    float mu = s * inv;
    float var = q * inv - mu * mu;
    float sc = gp[col] * rsqrtf(var + 1e-5f);
    int o = blockIdx.x ? 128 : 0;
    sb[o + col] = sc;
    sb[o + 64 + col] = bp[col] - mu * sc;
  }
}

// Node-layer BN: reduce per-block partials (782 x 256) -> scale/bias (128 cols)
__global__ void reduce_sb(const float* __restrict__ part,
                          const float* __restrict__ g, const float* __restrict__ b,
                          float* __restrict__ scale, float* __restrict__ bias) {
  int t = threadIdx.x;             // 1024
  int col = t & 127, slot = t >> 7; // 8 slots
  float s = 0.f, q = 0.f;
  for (int r = slot; r < 782; r += 8) {
    s += part[(size_t)r * 256 + col];
    q += part[(size_t)r * 256 + 128 + col];
  }
  __shared__ float ls[1024], lq[1024];
  ls[t] = s; lq[t] = q;
  __syncthreads();
  if (slot == 0) {
    #pragma unroll
    for (int i = 1; i < 8; ++i) { s += ls[i * 128 + col]; q += lq[i * 128 + col]; }
    float mu = s * (1.0f / NN);
    float var = q * (1.0f / NN) - mu * mu;
    float sc = g[col] * rsqrtf(var + 1e-5f);
    scale[col] = sc;
    bias[col] = b[col] - mu * sc;
  }
}

// ---------------------------------------------------------------------------
// CSR pass 1: count + rank in ONE atomic pass (rank = return value).
__global__ void rank_count(const int* __restrict__ dst, int* __restrict__ cnt,
                           int* __restrict__ rank) {
  int e = blockIdx.x * 256 + threadIdx.x;
  rank[e] = atomicAdd(&cnt[dst[e]], 1);
}

// ---------------------------------------------------------------------------
// Fused weight prep.
__global__ void wprep(const float* __restrict__ p_w1, const float* __restrict__ e_w1,
                      const float* __restrict__ p_w2, const float* __restrict__ e_w2,
                      const float* __restrict__ h_w1, const float* __restrict__ h_w2,
                      const float* __restrict__ h_w3, const float* __restrict__ h_w4,
                      unsigned short* __restrict__ wpab, unsigned short* __restrict__ wqab,
                      unsigned short* __restrict__ w1c_p, unsigned short* __restrict__ w1c_e,
                      unsigned short* __restrict__ w2f_p, unsigned short* __restrict__ w2f_e,
                      unsigned short* __restrict__ hw1t, unsigned short* __restrict__ hw2t,
                      unsigned short* __restrict__ hw3t, unsigned short* __restrict__ hw4t) {
  int gi = blockIdx.x * 256 + threadIdx.x;
  if (gi < 32768) {                        // wpab / wqab [256][64]
    const float* w = (gi < 16384) ? p_w1 : e_w1;
    unsigned short* o = (gi < 16384) ? wpab : wqab;
    int i = gi & 16383;
    int f = i >> 6, k = i & 63;
    int srcrow = k + ((f >> 7) << 6);
    o[i] = f2bf(w[(size_t)srcrow * 128 + (f & 127)]);
  } else if (gi < 49152) {                 // w1c_p / w1c_e [128][64]
    int i = (gi - 32768) & 8191;
    const float* w = (gi < 40960) ? (p_w1 + 128 * 128) : (e_w1 + 128 * 128);
    unsigned short* o = (gi < 40960) ? w1c_p : w1c_e;
    int f = i >> 6, k = i & 63;
    o[i] = f2bf(w[(size_t)k * 128 + f]);
  } else if (gi < 65536) {                 // w2f fragment-linear [kc][mb][lane][8]
    int i = (gi - 49152) & 8191;
    const float* w = (gi < 57344) ? p_w2 : e_w2;
    unsigned short* o = (gi < 57344) ? w2f_p : w2f_e;
    int j = i & 7, lane = (i >> 3) & 63, frag = i >> 9;
    int kc = frag >> 2, mb = frag & 3;
    int l15 = lane & 15, g = lane >> 4;
    o[i] = f2bf(w[(size_t)(kc * 32 + g * 8 + j) * 64 + 16 * mb + l15]);
  } else if (gi < 114688) {                // hw1t/hw2t/hw3t [128][128]
    int seg = (gi - 65536) >> 14;
    int i = (gi - 65536) & 16383;
    const float* w = (seg == 0) ? h_w1 : (seg == 1) ? h_w2 : h_w3;
    unsigned short* o = (seg == 0) ? hw1t : (seg == 1) ? hw2t : hw3t;
    int n = i >> 7, k = i & 127;
    o[i] = f2bf(w[(size_t)k * 128 + n]);
  } else if (gi < 122880) {                // hw4t [64][128]
    int i = gi - 114688;
    int n = i >> 7, k = i & 127;
    hw4t[i] = f2bf(h_w4[(size_t)k * 64 + n]);
  }
}

// ---------------------------------------------------------------------------
// single-block exclusive scan of cnt[NN] -> off (1024 threads, 49 nodes each)
__global__ void scan_offsets(const int* __restrict__ cnt, int* __restrict__ off) {
  __shared__ int ps[1024];
  const int NPT = (NN + 1023) / 1024;   // 49
  int t = threadIdx.x;
  int base = t * NPT;
  int end = base + NPT; if (end > NN) end = NN;
  int s = 0;
  for (int i = base; i < end; ++i) s += cnt[i];
  ps[t] = s;
  __syncthreads();
  for (int d = 1; d < 1024; d <<= 1) {
    int v = (t >= d) ? ps[t - d] : 0;
    __syncthreads();
    ps[t] += v;
    __syncthreads();
  }
  int pre = t ? ps[t - 1] : 0;
  for (int i = base; i < end; ++i) { off[i] = pre; pre += cnt[i]; }
  if (t == 1023) off[NN] = NE;
}

// ---------------------------------------------------------------------------
// CSR pass 2: placement via off[dst]+rank (NO atomics) + fused BN scatter.
__global__ void scatter_all(const float* __restrict__ ea, const float* __restrict__ sc,
                            const float* __restrict__ bi,
                            const int* __restrict__ srca, const int* __restrict__ dsta,
                            const int* __restrict__ off, const int* __restrict__ rank,
                            int* __restrict__ src_s, int* __restrict__ dst_s,
                            int* __restrict__ einv, unsigned short* __restrict__ vbf) {
  __shared__ int posl[256];
  int t = threadIdx.x;
  int e0 = blockIdx.x * 256;
  int e = e0 + t;
  int n = dsta[e];
  int pos = off[n] + rank[e];
  posl[t] = pos;
  src_s[pos] = srca[e];
  dst_s[pos] = n;
  einv[pos] = e;
  __syncthreads();
  #pragma unroll
  for (int it = 0; it < 8; ++it) {
    int task = it * 256 + t;
    int r = task >> 3, q = task & 7;
    int c8 = q * 8;
    const float4* px = (const float4*)(ea + (size_t)(e0 + r) * 64 + c8);
    float4 a = px[0], b2 = px[1];
    float4 s0 = *(const float4*)(sc + c8), s1 = *(const float4*)(sc + c8 + 4);
    float4 b0 = *(const float4*)(bi + c8),  b1 = *(const float4*)(bi + c8 + 4);
    unsigned short tmp[8];
    tmp[0] = f2bf(fmaxf(a.x * s0.x + b0.x, 0.f));
    tmp[1] = f2bf(fmaxf(a.y * s0.y + b0.y, 0.f));
    tmp[2] = f2bf(fmaxf(a.z * s0.z + b0.z, 0.f));
    tmp[3] = f2bf(fmaxf(a.w * s0.w + b0.w, 0.f));
    tmp[4] = f2bf(fmaxf(b2.x * s1.x + b1.x, 0.f));
    tmp[5] = f2bf(fmaxf(b2.y * s1.y + b1.y, 0.f));
    tmp[6] = f2bf(fmaxf(b2.z * s1.z + b1.z, 0.f));
    tmp[7] = f2bf(fmaxf(b2.w * s1.w + b1.w, 0.f));
    *(uint4*)(vbf + (size_t)posl[r] * 64 + c8) = *(uint4*)tmp;
  }
}

// ---------------------------------------------------------------------------
// PAB = bf16( relu(bn(in)) @ WT^T ), gather-swizzled out; also writes h (f32).
__global__ __launch_bounds__(256) void pab_gemm(
    const float* __restrict__ in, const float* __restrict__ sc,
    const float* __restrict__ bi, const unsigned short* __restrict__ WT,
    unsigned short* __restrict__ out, float* __restrict__ hout) {
  __shared__ __align__(16) unsigned short Ul[64 * 72];
  const int t = threadIdx.x;
  const int w = t >> 6, l = t & 63, g = l >> 4, l15 = l & 15;
  const int r0 = blockIdx.x * 64;

  #pragma unroll
  for (int it = 0; it < 2; ++it) {
    int idx = it * 256 + t;
    int r = idx >> 3, q = idx & 7;
    int row = r0 + r; int rr = row < NN ? row : NN - 1;
    float4 v = *(const float4*)(in + (size_t)rr * 64 + q * 8);
    float4 v2 = *(const float4*)(in + (size_t)rr * 64 + q * 8 + 4);
    float4 s0 = *(const float4*)(sc + q * 8), s1 = *(const float4*)(sc + q * 8 + 4);
    float4 c0 = *(const float4*)(bi + q * 8), c1 = *(const float4*)(bi + q * 8 + 4);
    v.x = fmaxf(v.x * s0.x + c0.x, 0.f);   v.y = fmaxf(v.y * s0.y + c0.y, 0.f);
    v.z = fmaxf(v.z * s0.z + c0.z, 0.f);   v.w = fmaxf(v.w * s0.w + c0.w, 0.f);
    v2.x = fmaxf(v2.x * s1.x + c1.x, 0.f); v2.y = fmaxf(v2.y * s1.y + c1.y, 0.f);
    v2.z = fmaxf(v2.z * s1.z + c1.z, 0.f); v2.w = fmaxf(v2.w * s1.w + c1.w, 0.f);
    unsigned short tmp[8];
    tmp[0] = f2bf(v.x);  tmp[1] = f2bf(v.y);  tmp[2] = f2bf(v.z);  tmp[3] = f2bf(v.w);
    tmp[4] = f2bf(v2.x); tmp[5] = f2bf(v2.y); tmp[6] = f2bf(v2.z); tmp[7] = f2bf(v2.w);
    *(uint4*)&Ul[r * 72 + q * 8] = *(uint4*)tmp;
    if (row < NN) {
      *(float4*)(hout + (size_t)row * 64 + q * 8) = v;
      *(float4*)(hout + (size_t)row * 64 + q * 8 + 4) = v2;
    }
  }
  us8 a[4][2];
  #pragma unroll
  for (int mm = 0; mm < 4; ++mm)
    #pragma unroll
    for (int kc = 0; kc < 2; ++kc)
      a[mm][kc] = *(const us8*)(WT + (size_t)(64 * w + 16 * mm + l15) * 64 + kc * 32 + g * 8);
  __syncthreads();

  f4 c[4][4];
  #pragma unroll
  for (int mm = 0; mm < 4; ++mm)
    #pragma unroll
    for (int nb = 0; nb < 4; ++nb)
      c[mm][nb] = (f4){0.f, 0.f, 0.f, 0.f};
  #pragma unroll
  for (int kc = 0; kc < 2; ++kc) {
    us8 bz[4];
    #pragma unroll
    for (int nb = 0; nb < 4; ++nb)
      bz[nb] = *(const us8*)&Ul[(16 * nb + l15) * 72 + kc * 32 + g * 8];
    #pragma unroll
    for (int mm = 0; mm < 4; ++mm)
      #pragma unroll
      for (int nb = 0; nb < 4; ++nb)
        c[mm][nb] = mfma16(a[mm][kc], bz[nb], c[mm][nb]);
  }
  #pragma unroll
  for (int mm = 0; mm < 4; ++mm)
    #pragma unroll
    for (int nb = 0; nb < 4; ++nb) {
      int row = r0 + 16 * nb + l15;
      if (row < NN) {
        int f0 = 64 * w + 16 * mm + 4 * g;
        int half = f0 >> 7;
        int f1 = f0 & 127;
        int pos = half * 128 + ((f1 >> 5) << 5) + (((f1 & 15) >> 2) << 3) + (((f1 >> 4) & 1) << 2);
        *(uint2*)(out + (size_t)row * 256 + pos) =
            pack4(c[mm][nb][0], c[mm][nb][1], c[mm][nb][2], c[mm][nb][3]);
      }
    }
}

// ---------------------------------------------------------------------------
// Edge MLP v5: 512 threads = 2 independent 64-edge groups sharing one W2 stage.
// CSR order both modes; V read direct from global; 1 barrier.
// MODE 1: m (bf16) contiguous out. MODE 2: v_out (f32) scatter via einv.
template<int MODE>
__global__ __launch_bounds__(512, 6) void edge_mlp5(
    const unsigned short* __restrict__ vbf,     // CSR-order rows
    const unsigned short* __restrict__ AB,      // swizzled PAB/QAB
    const int* __restrict__ idx0, const int* __restrict__ idx1,
    const int* __restrict__ einv,
    const unsigned short* __restrict__ W1cT, const float* __restrict__ B1,
    const unsigned short* __restrict__ W2F, const float* __restrict__ B2,
    void* __restrict__ outv) {
  __shared__ __align__(16) unsigned short Hl[2][64 * 136];
  __shared__ __align__(16) unsigned short W2l[8192];
  const int t = threadIdx.x;
  const int w = t >> 6, l = t & 63, g = l >> 4, l15 = l & 15;
  const int gi = w >> 2, w4 = w & 3;
  int bid = blockIdx.x;
  {  // bijective XCD-chunked swizzle (nwg=6250, 8 XCDs)
    const int q = 6250 / 8, r = 6250 % 8;
    int x = bid % 8, j = bid / 8;
    bid = (x < r ? x * (q + 1) : r * (q + 1) + (x - r) * q) + j;
  }
  const size_t e0 = (size_t)bid * 128 + (size_t)gi * 64;

  // ---- phase 0: gathers, W2->LDS, W1c frags, einv
  uint4 ga0[4], ga1[4];
  #pragma unroll
  for (int nb = 0; nb < 4; ++nb) {
    size_t e = e0 + 16 * nb + l15;
    int n0 = idx0[e], n1 = idx1[e];
    ga0[nb] = *(const uint4*)(AB + (size_t)n0 * 256 + w4 * 32 + g * 8);
    ga1[nb] = *(const uint4*)(AB + (size_t)n1 * 256 + 128 + w4 * 32 + g * 8);
  }
  int orig = 0;
  if (MODE == 2) orig = einv[e0 + 16 * w4 + l15];
  #pragma unroll
  for (int i = 0; i < 2; ++i) {
    int idx = t + 512 * i;
    *(uint4*)&W2l[idx * 8] = *(const uint4*)(W2F + (size_t)idx * 8);
  }
  us8 a1[2][2];
  #pragma unroll
  for (int mm = 0; mm < 2; ++mm)
    #pragma unroll
    for (int kc = 0; kc < 2; ++kc)
      a1[mm][kc] = *(const us8*)(W1cT + (size_t)(32 * w4 + 16 * mm + l15) * 64
                                 + kc * 32 + g * 8);

  // ---- phase 1: layer 1 MFMA, V directly from global (rows contiguous)
  f4 c1[2][4];
  #pragma unroll
  for (int mm = 0; mm < 2; ++mm)
    #pragma unroll
    for (int nb = 0; nb < 4; ++nb)
      c1[mm][nb] = (f4){0.f, 0.f, 0.f, 0.f};
  #pragma unroll
  for (int kc = 0; kc < 2; ++kc) {
    us8 bz[4];
    #pragma unroll
    for (int nb = 0; nb < 4; ++nb)
      bz[nb] = *(const us8*)(vbf + (e0 + 16 * nb + l15) * 64 + kc * 32 + g * 8);
    #pragma unroll
    for (int mm = 0; mm < 2; ++mm)
      #pragma unroll
      for (int nb = 0; nb < 4; ++nb)
        c1[mm][nb] = mfma16(a1[mm][kc], bz[nb], c1[mm][nb]);
  }

  // ---- phase 2: H = relu(c1 + B1 + ga0 + ga1) -> Hl[gi] (bf16)
  #pragma unroll
  for (int mm = 0; mm < 2; ++mm) {
    float4 bb = *(const float4*)(B1 + 32 * w4 + 16 * mm + 4 * g);
    #pragma unroll
    for (int nb = 0; nb < 4; ++nb) {
      f4 v = c1[mm][nb];
      unsigned int ux = mm ? ga0[nb].z : ga0[nb].x;
      unsigned int uy = mm ? ga0[nb].w : ga0[nb].y;
      unsigned int vx = mm ? ga1[nb].z : ga1[nb].x;
      unsigned int vy = mm ? ga1[nb].w : ga1[nb].y;
      float h0 = v[0] + bb.x + bf2f((unsigned short)(ux & 0xffff))
                             + bf2f((unsigned short)(vx & 0xffff));
      float h1 = v[1] + bb.y + bf2f((unsigned short)(ux >> 16))
                             + bf2f((unsigned short)(vx >> 16));
      float h2 = v[2] + bb.z + bf2f((unsigned short)(uy & 0xffff))
                             + bf2f((unsigned short)(vy & 0xffff));
      float h3 = v[3] + bb.w + bf2f((unsigned short)(uy >> 16))
                             + bf2f((unsigned short)(vy >> 16));
      int er = 16 * nb + l15;
      *(uint2*)&Hl[gi][er * 136 + 32 * w4 + 16 * mm + 4 * g] =
          pack4(fmaxf(h0, 0.f), fmaxf(h1, 0.f), fmaxf(h2, 0.f), fmaxf(h3, 0.f));
    }
  }
  __syncthreads();   // Hl + W2l ready

  // ---- phase 3: layer 2 (D2^T = W2^T * H^T)
  f4 c2[4];
  #pragma unroll
  for (int mb = 0; mb < 4; ++mb) {
    float4 bb = *(const float4*)(B2 + 16 * mb + 4 * g);
    c2[mb] = (f4){bb.x, bb.y, bb.z, bb.w};
  }
  #pragma unroll
  for (int kc = 0; kc < 4; ++kc) {
    us8 bh = *(const us8*)&Hl[gi][(16 * w4 + l15) * 136 + kc * 32 + g * 8];
    #pragma unroll
    for (int mb = 0; mb < 4; ++mb) {
      us8 a2 = *(const us8*)&W2l[((kc * 4 + mb) * 64 + l) * 8];
      c2[mb] = mfma16(a2, bh, c2[mb]);
    }
  }

  if (MODE == 1) {
    size_t e = e0 + 16 * w4 + l15;
    #pragma unroll
    for (int mb = 0; mb < 4; ++mb)
      *(uint2*)((unsigned short*)outv + e * 64 + 16 * mb + 4 * g) =
          pack4(c2[mb][0], c2[mb][1], c2[mb][2], c2[mb][3]);
  } else {
    #pragma unroll
    for (int mb = 0; mb < 4; ++mb)
      *(float4*)((float*)outv + (size_t)orig * 64 + 16 * mb + 4 * g) =
          (float4){c2[mb][0], c2[mb][1], c2[mb][2], c2[mb][3]};
  }
}

// ---------------------------------------------------------------------------
// Node GEMM, K=128, optional per-block column-stat partials (NO atomics).
// MODE 0: U = [in0(f32,64)|in1(f32,64)]. MODE 1: U = relu(in0*sc+bi), in0 bf16[128].
template<int MODE, int OUTW, bool OUTBF, bool STATS>
__global__ __launch_bounds__(256) void node_mfma(
    const void* __restrict__ in0v, const float* __restrict__ in1,
    const float* __restrict__ sc, const float* __restrict__ bi,
    const unsigned short* __restrict__ WT, const float* __restrict__ B,
    void* __restrict__ yv, float* __restrict__ part) {
  __shared__ __align__(16) unsigned short Ul[64 * 136];
  const int t = threadIdx.x;
  const int w = t >> 6, l = t & 63, g = l >> 4, l15 = l & 15;
  const int r0 = blockIdx.x * 64;
  constexpr int NMB = OUTW / 64;

  {
    int r = t >> 2, q = t & 3;
    int row = r0 + r;
    int rr = row < NN ? row : NN - 1;
    unsigned short tmp[32];
    if (MODE == 0) {
      const float* base = (q < 2) ? (const float*)in0v : in1;
      const float4* p = (const float4*)(base + (size_t)rr * 64 + (q & 1) * 32);
      #pragma unroll
      for (int i = 0; i < 8; ++i) {
        float4 v = p[i];
        tmp[4*i+0] = f2bf(v.x); tmp[4*i+1] = f2bf(v.y);
        tmp[4*i+2] = f2bf(v.z); tmp[4*i+3] = f2bf(v.w);
      }
    } else {
      const unsigned short* srcp = (const unsigned short*)in0v + (size_t)rr * 128 + q * 32;
      #pragma unroll
      for (int i = 0; i < 4; ++i) {
        uint4 u = *(const uint4*)(srcp + i * 8);
        const unsigned short* us = (const unsigned short*)&u;
        #pragma unroll
        for (int j2 = 0; j2 < 2; ++j2) {
          int cb = q * 32 + i * 8 + j2 * 4;
          float4 s = *(const float4*)(sc + cb);
          float4 b = *(const float4*)(bi + cb);
          tmp[i*8+j2*4+0] = f2bf(fmaxf(bf2f(us[j2*4+0]) * s.x + b.x, 0.f));
          tmp[i*8+j2*4+1] = f2bf(fmaxf(bf2f(us[j2*4+1]) * s.y + b.y, 0.f));
          tmp[i*8+j2*4+2] = f2bf(fmaxf(bf2f(us[j2*4+2]) * s.z + b.z, 0.f));
          tmp[i*8+j2*4+3] = f2bf(fmaxf(bf2f(us[j2*4+3]) * s.w + b.w, 0.f));
        }
      }
    }
    unsigned short* ur = &Ul[r * 136 + q * 32];
    #pragma unroll
    for (int i = 0; i < 4; ++i)
      *(uint4*)&ur[i * 8] = *(uint4*)(tmp + i * 8);
  }

  __syncthreads();

  f4 c[NMB][4];
  #pragma unroll
  for (int mm = 0; mm < NMB; ++mm) {
    float4 bb = *(const float4*)(B + 16 * (NMB * w + mm) + 4 * g);
    #pragma unroll
    for (int nb = 0; nb < 4; ++nb)
      c[mm][nb] = (f4){bb.x, bb.y, bb.z, bb.w};
  }

  #pragma unroll
  for (int kc = 0; kc < 4; ++kc) {
    us8 bu[4];
    #pragma unroll
    for (int nb = 0; nb < 4; ++nb)
      bu[nb] = *(const us8*)&Ul[(16 * nb + l15) * 136 + kc * 32 + g * 8];
    #pragma unroll
    for (int mm = 0; mm < NMB; ++mm) {
      us8 a = *(const us8*)(WT + (size_t)(16 * (NMB * w + mm) + l15) * 128
                            + kc * 32 + g * 8);
      #pragma unroll
      for (int nb = 0; nb < 4; ++nb)
        c[mm][nb] = mfma16(a, bu[nb], c[mm][nb]);
    }
  }

  #pragma unroll
  for (int mm = 0; mm < NMB; ++mm)
    #pragma unroll
    for (int nb = 0; nb < 4; ++nb) {
      int row = r0 + l15 + 16 * nb;
      if (row < NN) {
        int f0 = 16 * (NMB * w + mm) + 4 * g;
        if (OUTBF) {
          *(uint2*)((unsigned short*)yv + (size_t)row * OUTW + f0) =
              pack4(c[mm][nb][0], c[mm][nb][1], c[mm][nb][2], c[mm][nb][3]);
        } else {
          *(float4*)((float*)yv + (size_t)row * OUTW + f0) =
              (float4){c[mm][nb][0], c[mm][nb][1], c[mm][nb][2], c[mm][nb][3]};
        }
      }
    }

  if (STATS) {
    float msk[4];
    #pragma unroll
    for (int nb = 0; nb < 4; ++nb)
      msk[nb] = (r0 + 16 * nb + l15 < NN) ? 1.f : 0.f;
    #pragma unroll
    for (int mm = 0; mm < NMB; ++mm) {
      float sv[4], qv[4];
      #pragma unroll
      for (int r = 0; r < 4; ++r) {
        float s = 0.f, q = 0.f;
        #pragma unroll
        for (int nb = 0; nb < 4; ++nb) {
          float v = c[mm][nb][r] * msk[nb];
          s += v; q += v * v;
        }
        #pragma unroll
        for (int d = 1; d < 16; d <<= 1) {
          s += __shfl_xor(s, d);
          q += __shfl_xor(q, d);
        }
        sv[r] = s; qv[r] = q;
      }
      if (l15 == 0) {
        int f0 = 16 * (NMB * w + mm) + 4 * g;
        *(float4*)&part[(size_t)blockIdx.x * 256 + f0] =
            (float4){sv[0], sv[1], sv[2], sv[3]};
        *(float4*)&part[(size_t)blockIdx.x * 256 + 128 + f0] =
            (float4){qv[0], qv[1], qv[2], qv[3]};
      }
    }
  }
}

// ---------------------------------------------------------------------------
// Last node layer (bn(y)->relu -> @h_w4 -> h_out f32) + fused QAB epilogue.
__global__ __launch_bounds__(256) void node_last_qab(
    const unsigned short* __restrict__ in0, const float* __restrict__ sc,
    const float* __restrict__ bi,
    const unsigned short* __restrict__ WT, const float* __restrict__ B,
    const unsigned short* __restrict__ WQ,
    float* __restrict__ hout, unsigned short* __restrict__ QAB) {
  __shared__ __align__(16) unsigned short Ul[64 * 136];
  const int t = threadIdx.x;
  const int w = t >> 6, l = t & 63, g = l >> 4, l15 = l & 15;
  const int r0 = blockIdx.x * 64;

  {
    int r = t >> 2, q = t & 3;
    int row = r0 + r;
    int rr = row < NN ? row : NN - 1;
    unsigned short tmp[32];
    const unsigned short* srcp = in0 + (size_t)rr * 128 + q * 32;
    #pragma unroll
    for (int i = 0; i < 4; ++i) {
      uint4 u = *(const uint4*)(srcp + i * 8);
      const unsigned short* us = (const unsigned short*)&u;
      #pragma unroll
      for (int j2 = 0; j2 < 2; ++j2) {
        int cb = q * 32 + i * 8 + j2 * 4;
        float4 s = *(const float4*)(sc + cb);
        float4 b = *(const float4*)(bi + cb);
        tmp[i*8+j2*4+0] = f2bf(fmaxf(bf2f(us[j2*4+0]) * s.x + b.x, 0.f));
        tmp[i*8+j2*4+1] = f2bf(fmaxf(bf2f(us[j2*4+1]) * s.y + b.y, 0.f));
        tmp[i*8+j2*4+2] = f2bf(fmaxf(bf2f(us[j2*4+2]) * s.z + b.z, 0.f));
        tmp[i*8+j2*4+3] = f2bf(fmaxf(bf2f(us[j2*4+3]) * s.w + b.w, 0.f));
      }
    }
    unsigned short* ur = &Ul[r * 136 + q * 32];
    #pragma unroll
    for (int i = 0; i < 4; ++i)
      *(uint4*)&ur[i * 8] = *(uint4*)(tmp + i * 8);
  }

  __syncthreads();

  f4 c[4];
  {
    float4 bb = *(const float4*)(B + 16 * w + 4 * g);
    #pragma unroll
    for (int nb = 0; nb < 4; ++nb)
      c[nb] = (f4){bb.x, bb.y, bb.z, bb.w};
  }
  #pragma unroll
  for (int kc = 0; kc < 4; ++kc) {
    us8 bu[4];
    #pragma unroll
    for (int nb = 0; nb < 4; ++nb)
      bu[nb] = *(const us8*)&Ul[(16 * nb + l15) * 136 + kc * 32 + g * 8];
    us8 a = *(const us8*)(WT + (size_t)(16 * w + l15) * 128 + kc * 32 + g * 8);
    #pragma unroll
    for (int nb = 0; nb < 4; ++nb)
      c[nb] = mfma16(a, bu[nb], c[nb]);
  }

  #pragma unroll
  for (int nb = 0; nb < 4; ++nb) {
    int row = r0 + l15 + 16 * nb;
    if (row < NN) {
      int f0 = 16 * w + 4 * g;
      *(float4*)(hout + (size_t)row * 64 + f0) =
          (float4){c[nb][0], c[nb][1], c[nb][2], c[nb][3]};
    }
  }

  // ---- QAB epilogue: relu(h_out) @ WQ^T, swizzled out
  __syncthreads();   // everyone done reading Ul
  #pragma unroll
  for (int nb = 0; nb < 4; ++nb) {
    *(uint2*)&Ul[(16 * nb + l15) * 72 + 16 * w + 4 * g] =
        pack4(fmaxf(c[nb][0], 0.f), fmaxf(c[nb][1], 0.f),
              fmaxf(c[nb][2], 0.f), fmaxf(c[nb][3], 0.f));
  }
  us8 aq[4][2];
  #pragma unroll
  for (int mm = 0; mm < 4; ++mm)
    #pragma unroll
    for (int kc = 0; kc < 2; ++kc)
      aq[mm][kc] = *(const us8*)(WQ + (size_t)(64 * w + 16 * mm + l15) * 64 + kc * 32 + g * 8);
  __syncthreads();

  f4 cq[4][4];
  #pragma unroll
  for (int mm = 0; mm < 4; ++mm)
    #pragma unroll
    for (int nb = 0; nb < 4; ++nb)
      cq[mm][nb] = (f4){0.f, 0.f, 0.f, 0.f};
  #pragma unroll
  for (int kc = 0; kc < 2; ++kc) {
    us8 bz[4];
    #pragma unroll
    for (int nb = 0; nb < 4; ++nb)
      bz[nb] = *(const us8*)&Ul[(16 * nb + l15) * 72 + kc * 32 + g * 8];
    #pragma unroll
    for (int mm = 0; mm < 4; ++mm)
      #pragma unroll
      for (int nb = 0; nb < 4; ++nb)
        cq[mm][nb] = mfma16(aq[mm][kc], bz[nb], cq[mm][nb]);
  }
  #pragma unroll
  for (int mm = 0; mm < 4; ++mm)
    #pragma unroll
    for (int nb = 0; nb < 4; ++nb) {
      int row = r0 + 16 * nb + l15;
      if (row < NN) {
        int f0 = 64 * w + 16 * mm + 4 * g;
        int half = f0 >> 7;
        int f1 = f0 & 127;
        int pos = half * 128 + ((f1 >> 5) << 5) + (((f1 & 15) >> 2) << 3) + (((f1 >> 4) & 1) << 2);
        *(uint2*)(QAB + (size_t)row * 256 + pos) =
            pack4(cq[mm][nb][0], cq[mm][nb][1], cq[mm][nb][2], cq[mm][nb][3]);
      }
    }
}

// ---------------------------------------------------------------------------
// Per-node online scatter-softmax over CSR-contiguous m rows (bf16).
// Four independent online states (4 loads in flight), merged at the end.
__global__ void node_softmax(const unsigned short* __restrict__ m,
                             const int* __restrict__ off,
                             const float* __restrict__ tptr,
                             float* __restrict__ msg) {
  int gw = (blockIdx.x * 256 + threadIdx.x) >> 6;
  int lane = threadIdx.x & 63;
  if (gw >= NN) return;
  float t = tptr[0];
  int beg = off[gw], end = off[gw + 1];
  int len = end - beg;
  float M[4] = {-3e38f, -3e38f, -3e38f, -3e38f};
  float S[4] = {0.f, 0.f, 0.f, 0.f};
  float W[4] = {0.f, 0.f, 0.f, 0.f};
  int i = beg;
  for (; i + 3 < end; i += 4) {
    float v0 = bf2f(m[(size_t)(i + 0) * 64 + lane]);
    float v1 = bf2f(m[(size_t)(i + 1) * 64 + lane]);
    float v2 = bf2f(m[(size_t)(i + 2) * 64 + lane]);
    float v3 = bf2f(m[(size_t)(i + 3) * 64 + lane]);
    float s0 = v0 * t, s1 = v1 * t, s2 = v2 * t, s3 = v3 * t;
    float M0 = fmaxf(M[0], s0), M1 = fmaxf(M[1], s1);
    float M2 = fmaxf(M[2], s2), M3 = fmaxf(M[3], s3);
    float c0 = __expf(M[0] - M0), c1 = __expf(M[1] - M1);
    float c2 = __expf(M[2] - M2), c3 = __expf(M[3] - M3);
    float p0 = __expf(s0 - M0), p1 = __expf(s1 - M1);
    float p2 = __expf(s2 - M2), p3 = __expf(s3 - M3);
    S[0] = S[0] * c0 + p0;  W[0] = W[0] * c0 + v0 * p0;  M[0] = M0;
    S[1] = S[1] * c1 + p1;  W[1] = W[1] * c1 + v1 * p1;  M[1] = M1;
    S[2] = S[2] * c2 + p2;  W[2] = W[2] * c2 + v2 * p2;  M[2] = M2;
    S[3] = S[3] * c3 + p3;  W[3] = W[3] * c3 + v3 * p3;  M[3] = M3;
  }
  for (; i < end; ++i) {
    float v0 = bf2f(m[(size_t)i * 64 + lane]);
    float s0 = v0 * t;
    float M0 = fmaxf(M[0], s0);
    float c0 = __expf(M[0] - M0);
    float p0 = __expf(s0 - M0);
    S[0] = S[0] * c0 + p0;  W[0] = W[0] * c0 + v0 * p0;  M[0] = M0;
  }
  float Mn = fmaxf(fmaxf(M[0], M[1]), fmaxf(M[2], M[3]));
  float Sm = 0.f, Wm = 0.f;
  #pragma unroll
  for (int k = 0; k < 4; ++k) {
    float ck = __expf(M[k] - Mn);
    Sm += S[k] * ck;
    Wm += W[k] * ck;
  }
  msg[(size_t)gw * 64 + lane] = (len > 0) ? (Wm / Sm) : 0.f;
}

// ---------------------------------------------------------------------------
extern "C" void kernel_launch(void* const* d_in, const int* in_sizes, int n_in,
                              void* d_out, int out_size, void* d_ws, size_t ws_size,
                              hipStream_t stream) {
  const float* x     = (const float*)d_in[0];
  const int*   ei    = (const int*)d_in[1];
  const float* ea    = (const float*)d_in[2];
  const float* gh_w  = (const float*)d_in[3];
  const float* gh_b  = (const float*)d_in[4];
  const float* gv_w  = (const float*)d_in[5];
  const float* gv_b  = (const float*)d_in[6];
  const float* tpar  = (const float*)d_in[7];
  const float* p_w1  = (const float*)d_in[8];
  const float* p_b1  = (const float*)d_in[9];
  const float* p_w2  = (const float*)d_in[10];
  const float* p_b2  = (const float*)d_in[11];
  const float* h_w1  = (const float*)d_in[12];
  const float* h_b1  = (const float*)d_in[13];
  const float* h_g1  = (const float*)d_in[14];
  const float* h_bb1 = (const float*)d_in[15];
  const float* h_w2  = (const float*)d_in[16];
  const float* h_b2  = (const float*)d_in[17];
  const float* h_g2  = (const float*)d_in[18];
  const float* h_bb2 = (const float*)d_in[19];
  const float* h_w3  = (const float*)d_in[20];
  const float* h_b3  = (const float*)d_in[21];
  const float* h_g3  = (const float*)d_in[22];
  const float* h_bb3 = (const float*)d_in[23];
  const float* h_w4  = (const float*)d_in[24];
  const float* h_b4  = (const float*)d_in[25];
  const float* e_w1  = (const float*)d_in[26];
  const float* e_b1  = (const float*)d_in[27];
  const float* e_w2  = (const float*)d_in[28];
  const float* e_b2  = (const float*)d_in[29];

  float* h_out = (float*)d_out;
  float* v_out = (float*)d_out + (size_t)NN * 64;

  const int* src = ei;
  const int* dst = ei + NE;

  char* w = (char*)d_ws;
  int* cnt = (int*)w;                       // 200704 B, zeroed
  size_t zero_bytes = 200704;

  char* p = w + zero_bytes;
  float* sb = (float*)p; p += 4096;
  float* sbx_s = sb,       *sbx_b = sb + 64;
  float* sbv_s = sb + 128, *sbv_b = sb + 192;
  float* sb1_s = sb + 256, *sb1_b = sb + 384;
  float* sb2_s = sb + 512, *sb2_b = sb + 640;
  float* sb3_s = sb + 768, *sb3_b = sb + 896;
  float* pstat = (float*)p; p += 1280 * 128 * 4;
  float* npart = (float*)p; p += 782 * 256 * 4;
  int* off    = (int*)p; p += 200704;
  int* rank   = (int*)p; p += (size_t)NE * 4;
  int* einv   = (int*)p; p += (size_t)NE * 4;
  int* src_s  = (int*)p; p += (size_t)NE * 4;
  int* dst_s  = (int*)p; p += (size_t)NE * 4;
  float* h    = (float*)p; p += (size_t)NN * 64 * 4;
  float* msg  = (float*)p; p += (size_t)NN * 64 * 4;
  unsigned short* vbf  = (unsigned short*)p; p += (size_t)NE * 64 * 2;
  unsigned short* m_bf = (unsigned short*)p; p += (size_t)NE * 64 * 2;
  unsigned short* PAB  = (unsigned short*)p; p += (size_t)NN * 256 * 2;
  unsigned short* QAB  = (unsigned short*)p; p += (size_t)NN * 256 * 2;
  unsigned short* y1   = (unsigned short*)p; p += (size_t)NN * 128 * 2;
  unsigned short* y2   = (unsigned short*)p; p += (size_t)NN * 128 * 2;
  unsigned short* wpab  = (unsigned short*)p; p += 256 * 64 * 2;
  unsigned short* wqab  = (unsigned short*)p; p += 256 * 64 * 2;
  unsigned short* w1c_p = (unsigned short*)p; p += 128 * 64 * 2;
  unsigned short* w1c_e = (unsigned short*)p; p += 128 * 64 * 2;
  unsigned short* w2f_p = (unsigned short*)p; p += 64 * 128 * 2;
  unsigned short* w2f_e = (unsigned short*)p; p += 64 * 128 * 2;
  unsigned short* h_w1t = (unsigned short*)p; p += 128 * 128 * 2;
  unsigned short* h_w2t = (unsigned short*)p; p += 128 * 128 * 2;
  unsigned short* h_w3t = (unsigned short*)p; p += 128 * 128 * 2;
  unsigned short* h_w4t = (unsigned short*)p; p += 64 * 128 * 2;

  hipMemsetAsync(d_ws, 0, zero_bytes, stream);

  wprep<<<480, 256, 0, stream>>>(p_w1, e_w1, p_w2, e_w2, h_w1, h_w2, h_w3, h_w4,
                                 wpab, wqab, w1c_p, w1c_e, w2f_p, w2f_e,
                                 h_w1t, h_w2t, h_w3t, h_w4t);

  // BN stats: partials (no atomics) + reduce
  prep_stats<<<1280, 256, 0, stream>>>(x, ea, pstat);

  // CSR pass 1: count + rank in one atomic pass
  rank_count<<<3125, 256, 0, stream>>>(dst, cnt, rank);

  // single-block scan
  scan_offsets<<<1, 1024, 0, stream>>>(cnt, off);

  reduce_stats<<<2, 1024, 0, stream>>>(pstat, gh_w, gh_b, gv_w, gv_b, sb);

  // CSR pass 2: atomic-free placement + fused BN scatter of edge_attr
  scatter_all<<<3125, 256, 0, stream>>>(ea, sbv_s, sbv_b, src, dst, off, rank,
                                        src_s, dst_s, einv, vbf);

  // node-side factor: PAB = relu(bn(x)) @ [pW1a|pW1b]; also writes h
  pab_gemm<<<782, 256, 0, stream>>>(x, sbx_s, sbx_b, wpab, PAB, h);

  // message MLP (CSR order): table0 = dst (pW1a), table1 = src (pW1b)
  edge_mlp5<1><<<6250, 512, 0, stream>>>(vbf, PAB, dst_s, src_s, einv,
                                         w1c_p, p_b1, w2f_p, p_b2, (void*)m_bf);

  node_softmax<<<12500, 256, 0, stream>>>(m_bf, off, tpar, msg);

  // node MLP chain: per-block stat partials + tiny reduce (no atomics)
  node_mfma<0, 128, true, true><<<782, 256, 0, stream>>>(
      h, msg, nullptr, nullptr, h_w1t, h_b1, (void*)y1, npart);
  reduce_sb<<<1, 1024, 0, stream>>>(npart, h_g1, h_bb1, sb1_s, sb1_b);

  node_mfma<1, 128, true, true><<<782, 256, 0, stream>>>(
      y1, nullptr, sb1_s, sb1_b, h_w2t, h_b2, (void*)y2, npart);
  reduce_sb<<<1, 1024, 0, stream>>>(npart, h_g2, h_bb2, sb2_s, sb2_b);

  node_mfma<1, 128, true, true><<<782, 256, 0, stream>>>(
      y2, nullptr, sb2_s, sb2_b, h_w3t, h_b3, (void*)y1, npart);
  reduce_sb<<<1, 1024, 0, stream>>>(npart, h_g3, h_bb3, sb3_s, sb3_b);

  // last layer + fused QAB = relu(h_out) @ [eW1a|eW1b]
  node_last_qab<<<782, 256, 0, stream>>>(y1, sb3_s, sb3_b, h_w4t, h_b4, wqab,
                                         h_out, QAB);

  // edge output MLP (CSR order): table0 = src (eW1a), table1 = dst (eW1b)
  edge_mlp5<2><<<6250, 512, 0, stream>>>(vbf, QAB, src_s, dst_s, einv,
                                         w1c_e, e_b1, w2f_e, e_b2, (void*)v_out);
}

// Round 12
// 800.948 us; speedup vs baseline: 1.1296x; 1.1296x over previous
//
#include <hip/hip_runtime.h>
#include <math.h>

#define NN 50000
#define NE 800000

typedef __attribute__((ext_vector_type(8))) unsigned short us8;
typedef __attribute__((ext_vector_type(8))) __bf16 bf8;
typedef __attribute__((ext_vector_type(4))) float f4;

__device__ __forceinline__ unsigned short f2bf(float f) {
  unsigned int u = __float_as_uint(f);
  unsigned int r = u + 0x7FFFu + ((u >> 16) & 1u);
  return (unsigned short)(r >> 16);
}
__device__ __forceinline__ float bf2f(unsigned short h) {
  return __uint_as_float(((unsigned int)h) << 16);
}
__device__ __forceinline__ f4 mfma16(us8 a, us8 b, f4 c) {
  return __builtin_amdgcn_mfma_f32_16x16x32_bf16(
      __builtin_bit_cast(bf8, a), __builtin_bit_cast(bf8, b), c, 0, 0, 0);
}
__device__ __forceinline__ uint2 pack4(float a, float b, float c, float d) {
  uint2 r;
  r.x = (unsigned)f2bf(a) | ((unsigned)f2bf(b) << 16);
  r.y = (unsigned)f2bf(c) | ((unsigned)f2bf(d) << 16);
  return r;
}

// ---------------------------------------------------------------------------
// Fused prep: blocks [0,256) = x stats, [256,1280) = ea stats (per-block
// partials, no atomics), [1280,4405) = CSR count+rank (one atomic pass).
__global__ void prep_all(const float* __restrict__ x, const float* __restrict__ ea,
                         const int* __restrict__ dst,
                         float* __restrict__ pstat, int* __restrict__ cnt,
                         int* __restrict__ rank) {
  int b = blockIdx.x;
  int t = threadIdx.x;
  if (b >= 1280) {                 // count + rank
    int e = (b - 1280) * 256 + t;
    rank[e] = atomicAdd(&cnt[dst[e]], 1);
    return;
  }
  const float* srcp; int rows; int nblk, b0;
  if (b < 256) { srcp = x;  rows = NN; nblk = 256;  b0 = b; }
  else         { srcp = ea; rows = NE; nblk = 1024; b0 = b - 256; }
  int cg = (t & 15) * 4;           // column group (4 cols)
  int rs = t >> 4;                 // row slot 0..15
  float4 s = {0.f, 0.f, 0.f, 0.f}, q = {0.f, 0.f, 0.f, 0.f};
  for (int r = b0 * 64 + rs; r < rows; r += nblk * 64) {
    #pragma unroll
    for (int u = 0; u < 4; ++u) {
      int rr = r + u * 16;
      if (rr < rows) {
        float4 v = *(const float4*)(srcp + (size_t)rr * 64 + cg);
        s.x += v.x; s.y += v.y; s.z += v.z; s.w += v.w;
        q.x += v.x * v.x; q.y += v.y * v.y; q.z += v.z * v.z; q.w += v.w * v.w;
      }
    }
  }
  __shared__ float4 ls[256], lq[256];
  ls[t] = s; lq[t] = q;
  __syncthreads();
  if (rs == 0) {
    #pragma unroll
    for (int i = 1; i < 16; ++i) {
      float4 a = ls[i * 16 + t], z = lq[i * 16 + t];
      s.x += a.x; s.y += a.y; s.z += a.z; s.w += a.w;
      q.x += z.x; q.y += z.y; q.z += z.z; q.w += z.w;
    }
    *(float4*)&pstat[(size_t)b * 128 + cg] = s;
    *(float4*)&pstat[(size_t)b * 128 + 64 + cg] = q;
  }
}

// BN stats pass 2: reduce partials -> scale/bias. block 0 = x, block 1 = ea.
__global__ void reduce_stats(const float* __restrict__ pstat,
                             const float* __restrict__ gh_w, const float* __restrict__ gh_b,
                             const float* __restrict__ gv_w, const float* __restrict__ gv_b,
                             float* __restrict__ sb) {
  int t = threadIdx.x;             // 1024
  int col = t & 63, slot = t >> 6; // 16 slots
  int base = blockIdx.x ? 256 : 0;
  int n = blockIdx.x ? 1024 : 256;
  float s = 0.f, q = 0.f;
  for (int r = slot; r < n; r += 16) {
    s += pstat[(size_t)(base + r) * 128 + col];
    q += pstat[(size_t)(base + r) * 128 + 64 + col];
  }
  __shared__ float ls[1024], lq[1024];
  ls[t] = s; lq[t] = q;
  __syncthreads();
  if (slot == 0) {
    #pragma unroll
    for (int i = 1; i < 16; ++i) { s += ls[i * 64 + col]; q += lq[i * 64 + col]; }
    float inv = blockIdx.x ? (1.0f / NE) : (1.0f / NN);
    const float* gp = blockIdx.x ? gv_w : gh_w;
    const float* bp = blockIdx.x ? gv_b : gh_b;
    float mu = s * inv;
    float var = q * inv - mu * mu;
    float sc = gp[col] * rsqrtf(var + 1e-5f);
    int o = blockIdx.x ? 128 : 0;
    sb[o + col] = sc;
    sb[o + 64 + col] = bp[col] - mu * sc;
  }
}

// Node-layer BN: reduce per-block partials (782 x 256) -> scale/bias (128 cols)
__global__ void reduce_sb(const float* __restrict__ part,
                          const float* __restrict__ g, const float* __restrict__ b,
                          float* __restrict__ scale, float* __restrict__ bias) {
  int t = threadIdx.x;             // 1024
  int col = t & 127, slot = t >> 7; // 8 slots
  float s = 0.f, q = 0.f;
  for (int r = slot; r < 782; r += 8) {
    s += part[(size_t)r * 256 + col];
    q += part[(size_t)r * 256 + 128 + col];
  }
  __shared__ float ls[1024], lq[1024];
  ls[t] = s; lq[t] = q;
  __syncthreads();
  if (slot == 0) {
    #pragma unroll
    for (int i = 1; i < 8; ++i) { s += ls[i * 128 + col]; q += lq[i * 128 + col]; }
    float mu = s * (1.0f / NN);
    float var = q * (1.0f / NN) - mu * mu;
    float sc = g[col] * rsqrtf(var + 1e-5f);
    scale[col] = sc;
    bias[col] = b[col] - mu * sc;
  }
}

// ---------------------------------------------------------------------------
// Fused weight prep.
__global__ void wprep(const float* __restrict__ p_w1, const float* __restrict__ e_w1,
                      const float* __restrict__ p_w2, const float* __restrict__ e_w2,
                      const float* __restrict__ h_w1, const float* __restrict__ h_w2,
                      const float* __restrict__ h_w3, const float* __restrict__ h_w4,
                      unsigned short* __restrict__ wpab, unsigned short* __restrict__ wqab,
                      unsigned short* __restrict__ w1c_p, unsigned short* __restrict__ w1c_e,
                      unsigned short* __restrict__ w2f_p, unsigned short* __restrict__ w2f_e,
                      unsigned short* __restrict__ hw1t, unsigned short* __restrict__ hw2t,
                      unsigned short* __restrict__ hw3t, unsigned short* __restrict__ hw4t) {
  int gi = blockIdx.x * 256 + threadIdx.x;
  if (gi < 32768) {                        // wpab / wqab [256][64]
    const float* w = (gi < 16384) ? p_w1 : e_w1;
    unsigned short* o = (gi < 16384) ? wpab : wqab;
    int i = gi & 16383;
    int f = i >> 6, k = i & 63;
    int srcrow = k + ((f >> 7) << 6);
    o[i] = f2bf(w[(size_t)srcrow * 128 + (f & 127)]);
  } else if (gi < 49152) {                 // w1c_p / w1c_e [128][64]
    int i = (gi - 32768) & 8191;
    const float* w = (gi < 40960) ? (p_w1 + 128 * 128) : (e_w1 + 128 * 128);
    unsigned short* o = (gi < 40960) ? w1c_p : w1c_e;
    int f = i >> 6, k = i & 63;
    o[i] = f2bf(w[(size_t)k * 128 + f]);
  } else if (gi < 65536) {                 // w2f fragment-linear [kc][mb][lane][8]
    int i = (gi - 49152) & 8191;
    const float* w = (gi < 57344) ? p_w2 : e_w2;
    unsigned short* o = (gi < 57344) ? w2f_p : w2f_e;
    int j = i & 7, lane = (i >> 3) & 63, frag = i >> 9;
    int kc = frag >> 2, mb = frag & 3;
    int l15 = lane & 15, g = lane >> 4;
    o[i] = f2bf(w[(size_t)(kc * 32 + g * 8 + j) * 64 + 16 * mb + l15]);
  } else if (gi < 114688) {                // hw1t/hw2t/hw3t [128][128]
    int seg = (gi - 65536) >> 14;
    int i = (gi - 65536) & 16383;
    const float* w = (seg == 0) ? h_w1 : (seg == 1) ? h_w2 : h_w3;
    unsigned short* o = (seg == 0) ? hw1t : (seg == 1) ? hw2t : hw3t;
    int n = i >> 7, k = i & 127;
    o[i] = f2bf(w[(size_t)k * 128 + n]);
  } else if (gi < 122880) {                // hw4t [64][128]
    int i = gi - 114688;
    int n = i >> 7, k = i & 127;
    hw4t[i] = f2bf(h_w4[(size_t)k * 64 + n]);
  }
}

// ---------------------------------------------------------------------------
// hierarchical scan
__global__ void scan_part(const int* __restrict__ cnt, int* __restrict__ bsum) {
  __shared__ int ls[256];
  int i = blockIdx.x * 256 + threadIdx.x;
  ls[threadIdx.x] = (i < NN) ? cnt[i] : 0;
  __syncthreads();
  for (int d = 128; d > 0; d >>= 1) {
    if (threadIdx.x < d) ls[threadIdx.x] += ls[threadIdx.x + d];
    __syncthreads();
  }
  if (threadIdx.x == 0) bsum[blockIdx.x] = ls[0];
}

__global__ void scan_top(int* __restrict__ bsum) {
  __shared__ int ps[256];
  int t = threadIdx.x;
  int v = (t < 196) ? bsum[t] : 0;
  ps[t] = v;
  __syncthreads();
  for (int d = 1; d < 256; d <<= 1) {
    int tv = (t >= d) ? ps[t - d] : 0;
    __syncthreads();
    ps[t] += tv;
    __syncthreads();
  }
  if (t < 196) bsum[t] = ps[t] - v;   // exclusive
}

__global__ void scan_add(const int* __restrict__ cnt, const int* __restrict__ bsum,
                         int* __restrict__ off) {
  __shared__ int ps[256];
  int t = threadIdx.x;
  int i = blockIdx.x * 256 + t;
  int v = (i < NN) ? cnt[i] : 0;
  ps[t] = v;
  __syncthreads();
  for (int d = 1; d < 256; d <<= 1) {
    int tv = (t >= d) ? ps[t - d] : 0;
    __syncthreads();
    ps[t] += tv;
    __syncthreads();
  }
  if (i < NN) off[i] = bsum[blockIdx.x] + ps[t] - v;
  if (blockIdx.x == 0 && t == 0) off[NN] = NE;
}

// ---------------------------------------------------------------------------
// CSR pass 2: placement via off[dst]+rank (NO atomics) + fused BN scatter.
__global__ void scatter_all(const float* __restrict__ ea, const float* __restrict__ sc,
                            const float* __restrict__ bi,
                            const int* __restrict__ srca, const int* __restrict__ dsta,
                            const int* __restrict__ off, const int* __restrict__ rank,
                            int* __restrict__ src_s, int* __restrict__ dst_s,
                            int* __restrict__ einv, unsigned short* __restrict__ vbf) {
  __shared__ int posl[256];
  int t = threadIdx.x;
  int e0 = blockIdx.x * 256;
  int e = e0 + t;
  int n = dsta[e];
  int pos = off[n] + rank[e];
  posl[t] = pos;
  src_s[pos] = srca[e];
  dst_s[pos] = n;
  einv[pos] = e;
  __syncthreads();
  #pragma unroll
  for (int it = 0; it < 8; ++it) {
    int task = it * 256 + t;
    int r = task >> 3, q = task & 7;
    int c8 = q * 8;
    const float4* px = (const float4*)(ea + (size_t)(e0 + r) * 64 + c8);
    float4 a = px[0], b2 = px[1];
    float4 s0 = *(const float4*)(sc + c8), s1 = *(const float4*)(sc + c8 + 4);
    float4 b0 = *(const float4*)(bi + c8),  b1 = *(const float4*)(bi + c8 + 4);
    unsigned short tmp[8];
    tmp[0] = f2bf(fmaxf(a.x * s0.x + b0.x, 0.f));
    tmp[1] = f2bf(fmaxf(a.y * s0.y + b0.y, 0.f));
    tmp[2] = f2bf(fmaxf(a.z * s0.z + b0.z, 0.f));
    tmp[3] = f2bf(fmaxf(a.w * s0.w + b0.w, 0.f));
    tmp[4] = f2bf(fmaxf(b2.x * s1.x + b1.x, 0.f));
    tmp[5] = f2bf(fmaxf(b2.y * s1.y + b1.y, 0.f));
    tmp[6] = f2bf(fmaxf(b2.z * s1.z + b1.z, 0.f));
    tmp[7] = f2bf(fmaxf(b2.w * s1.w + b1.w, 0.f));
    *(uint4*)(vbf + (size_t)posl[r] * 64 + c8) = *(uint4*)tmp;
  }
}

// ---------------------------------------------------------------------------
// PAB = bf16( relu(bn(in)) @ WT^T ), gather-swizzled out; also writes h (f32).
__global__ __launch_bounds__(256) void pab_gemm(
    const float* __restrict__ in, const float* __restrict__ sc,
    const float* __restrict__ bi, const unsigned short* __restrict__ WT,
    unsigned short* __restrict__ out, float* __restrict__ hout) {
  __shared__ __align__(16) unsigned short Ul[64 * 72];
  const int t = threadIdx.x;
  const int w = t >> 6, l = t & 63, g = l >> 4, l15 = l & 15;
  const int r0 = blockIdx.x * 64;

  #pragma unroll
  for (int it = 0; it < 2; ++it) {
    int idx = it * 256 + t;
    int r = idx >> 3, q = idx & 7;
    int row = r0 + r; int rr = row < NN ? row : NN - 1;
    float4 v = *(const float4*)(in + (size_t)rr * 64 + q * 8);
    float4 v2 = *(const float4*)(in + (size_t)rr * 64 + q * 8 + 4);
    float4 s0 = *(const float4*)(sc + q * 8), s1 = *(const float4*)(sc + q * 8 + 4);
    float4 c0 = *(const float4*)(bi + q * 8), c1 = *(const float4*)(bi + q * 8 + 4);
    v.x = fmaxf(v.x * s0.x + c0.x, 0.f);   v.y = fmaxf(v.y * s0.y + c0.y, 0.f);
    v.z = fmaxf(v.z * s0.z + c0.z, 0.f);   v.w = fmaxf(v.w * s0.w + c0.w, 0.f);
    v2.x = fmaxf(v2.x * s1.x + c1.x, 0.f); v2.y = fmaxf(v2.y * s1.y + c1.y, 0.f);
    v2.z = fmaxf(v2.z * s1.z + c1.z, 0.f); v2.w = fmaxf(v2.w * s1.w + c1.w, 0.f);
    unsigned short tmp[8];
    tmp[0] = f2bf(v.x);  tmp[1] = f2bf(v.y);  tmp[2] = f2bf(v.z);  tmp[3] = f2bf(v.w);
    tmp[4] = f2bf(v2.x); tmp[5] = f2bf(v2.y); tmp[6] = f2bf(v2.z); tmp[7] = f2bf(v2.w);
    *(uint4*)&Ul[r * 72 + q * 8] = *(uint4*)tmp;
    if (row < NN) {
      *(float4*)(hout + (size_t)row * 64 + q * 8) = v;
      *(float4*)(hout + (size_t)row * 64 + q * 8 + 4) = v2;
    }
  }
  us8 a[4][2];
  #pragma unroll
  for (int mm = 0; mm < 4; ++mm)
    #pragma unroll
    for (int kc = 0; kc < 2; ++kc)
      a[mm][kc] = *(const us8*)(WT + (size_t)(64 * w + 16 * mm + l15) * 64 + kc * 32 + g * 8);
  __syncthreads();

  f4 c[4][4];
  #pragma unroll
  for (int mm = 0; mm < 4; ++mm)
    #pragma unroll
    for (int nb = 0; nb < 4; ++nb)
      c[mm][nb] = (f4){0.f, 0.f, 0.f, 0.f};
  #pragma unroll
  for (int kc = 0; kc < 2; ++kc) {
    us8 bz[4];
    #pragma unroll
    for (int nb = 0; nb < 4; ++nb)
      bz[nb] = *(const us8*)&Ul[(16 * nb + l15) * 72 + kc * 32 + g * 8];
    #pragma unroll
    for (int mm = 0; mm < 4; ++mm)
      #pragma unroll
      for (int nb = 0; nb < 4; ++nb)
        c[mm][nb] = mfma16(a[mm][kc], bz[nb], c[mm][nb]);
  }
  #pragma unroll
  for (int mm = 0; mm < 4; ++mm)
    #pragma unroll
    for (int nb = 0; nb < 4; ++nb) {
      int row = r0 + 16 * nb + l15;
      if (row < NN) {
        int f0 = 64 * w + 16 * mm + 4 * g;
        int half = f0 >> 7;
        int f1 = f0 & 127;
        int pos = half * 128 + ((f1 >> 5) << 5) + (((f1 & 15) >> 2) << 3) + (((f1 >> 4) & 1) << 2);
        *(uint2*)(out + (size_t)row * 256 + pos) =
            pack4(c[mm][nb][0], c[mm][nb][1], c[mm][nb][2], c[mm][nb][3]);
      }
    }
}

// ---------------------------------------------------------------------------
// Edge MLP v6: 256 threads, 128 edges/block in 2 pipelined halves sharing one
// W2 LDS stage. CSR order; V direct from global. half-2 gathers issued before
// half-1's layer-2 barrier (latency hidden under MFMA).
// MODE 1: m (bf16) contiguous out. MODE 2: v_out (f32) scatter via einv.
template<int MODE>
__global__ __launch_bounds__(256, 4) void edge_mlp6(
    const unsigned short* __restrict__ vbf,     // CSR-order rows
    const unsigned short* __restrict__ AB,      // swizzled PAB/QAB
    const int* __restrict__ idx0, const int* __restrict__ idx1,
    const int* __restrict__ einv,
    const unsigned short* __restrict__ W1cT, const float* __restrict__ B1,
    const unsigned short* __restrict__ W2F, const float* __restrict__ B2,
    void* __restrict__ outv) {
  __shared__ __align__(16) unsigned short Hl[64 * 136];
  __shared__ __align__(16) unsigned short W2l[8192];
  const int t = threadIdx.x;
  const int w = t >> 6, l = t & 63, g = l >> 4, l15 = l & 15;
  int bid = blockIdx.x;
  {  // bijective XCD-chunked swizzle (nwg=6250, 8 XCDs)
    const int q = 6250 / 8, r = 6250 % 8;
    int x = bid % 8, j = bid / 8;
    bid = (x < r ? x * (q + 1) : r * (q + 1) + (x - r) * q) + j;
  }
  const size_t eb = (size_t)bid * 128;

  // ---- phase 0: half-0 gathers, W2->LDS, W1c frags, einv (both halves)
  uint4 ga0[4], ga1[4];
  #pragma unroll
  for (int nb = 0; nb < 4; ++nb) {
    size_t e = eb + 16 * nb + l15;
    int n0 = idx0[e], n1 = idx1[e];
    ga0[nb] = *(const uint4*)(AB + (size_t)n0 * 256 + w * 32 + g * 8);
    ga1[nb] = *(const uint4*)(AB + (size_t)n1 * 256 + 128 + w * 32 + g * 8);
  }
  int orig_h[2] = {0, 0};
  if (MODE == 2) {
    orig_h[0] = einv[eb + 16 * w + l15];
    orig_h[1] = einv[eb + 64 + 16 * w + l15];
  }
  #pragma unroll
  for (int i = 0; i < 4; ++i) {
    uint4 v = *(const uint4*)(W2F + (size_t)(t + 256 * i) * 8);
    *(uint4*)&W2l[(t + 256 * i) * 8] = v;
  }
  us8 a1[2][2];
  #pragma unroll
  for (int mm = 0; mm < 2; ++mm)
    #pragma unroll
    for (int kc = 0; kc < 2; ++kc)
      a1[mm][kc] = *(const us8*)(W1cT + (size_t)(32 * w + 16 * mm + l15) * 64
                                 + kc * 32 + g * 8);

  #pragma unroll
  for (int hf = 0; hf < 2; ++hf) {
    const size_t e0 = eb + (size_t)hf * 64;

    // ---- layer 1 MFMA, V directly from global (rows contiguous)
    f4 c1[2][4];
    #pragma unroll
    for (int mm = 0; mm < 2; ++mm)
      #pragma unroll
      for (int nb = 0; nb < 4; ++nb)
        c1[mm][nb] = (f4){0.f, 0.f, 0.f, 0.f};
    #pragma unroll
    for (int kc = 0; kc < 2; ++kc) {
      us8 bz[4];
      #pragma unroll
      for (int nb = 0; nb < 4; ++nb)
        bz[nb] = *(const us8*)(vbf + (e0 + 16 * nb + l15) * 64 + kc * 32 + g * 8);
      #pragma unroll
      for (int mm = 0; mm < 2; ++mm)
        #pragma unroll
        for (int nb = 0; nb < 4; ++nb)
          c1[mm][nb] = mfma16(a1[mm][kc], bz[nb], c1[mm][nb]);
    }

    // ---- H = relu(c1 + B1 + ga0 + ga1) -> Hl (bf16), consumes gathers
    #pragma unroll
    for (int mm = 0; mm < 2; ++mm) {
      float4 bb = *(const float4*)(B1 + 32 * w + 16 * mm + 4 * g);
      #pragma unroll
      for (int nb = 0; nb < 4; ++nb) {
        f4 v = c1[mm][nb];
        unsigned int ux = mm ? ga0[nb].z : ga0[nb].x;
        unsigned int uy = mm ? ga0[nb].w : ga0[nb].y;
        unsigned int vx = mm ? ga1[nb].z : ga1[nb].x;
        unsigned int vy = mm ? ga1[nb].w : ga1[nb].y;
        float h0 = v[0] + bb.x + bf2f((unsigned short)(ux & 0xffff))
                               + bf2f((unsigned short)(vx & 0xffff));
        float h1 = v[1] + bb.y + bf2f((unsigned short)(ux >> 16))
                               + bf2f((unsigned short)(vx >> 16));
        float h2 = v[2] + bb.z + bf2f((unsigned short)(uy & 0xffff))
                               + bf2f((unsigned short)(vy & 0xffff));
        float h3 = v[3] + bb.w + bf2f((unsigned short)(uy >> 16))
                               + bf2f((unsigned short)(vy >> 16));
        int er = 16 * nb + l15;
        *(uint2*)&Hl[er * 136 + 32 * w + 16 * mm + 4 * g] =
            pack4(fmaxf(h0, 0.f), fmaxf(h1, 0.f), fmaxf(h2, 0.f), fmaxf(h3, 0.f));
      }
    }

    // issue half-1 gathers now (in flight across the next two barriers)
    if (hf == 0) {
      #pragma unroll
      for (int nb = 0; nb < 4; ++nb) {
        size_t e = eb + 64 + 16 * nb + l15;
        int n0 = idx0[e], n1 = idx1[e];
        ga0[nb] = *(const uint4*)(AB + (size_t)n0 * 256 + w * 32 + g * 8);
        ga1[nb] = *(const uint4*)(AB + (size_t)n1 * 256 + 128 + w * 32 + g * 8);
      }
    }
    __syncthreads();   // Hl (+W2l on hf=0) ready

    // ---- layer 2 (D2^T = W2^T * H^T)
    f4 c2[4];
    #pragma unroll
    for (int mb = 0; mb < 4; ++mb) {
      float4 bb = *(const float4*)(B2 + 16 * mb + 4 * g);
      c2[mb] = (f4){bb.x, bb.y, bb.z, bb.w};
    }
    #pragma unroll
    for (int kc = 0; kc < 4; ++kc) {
      us8 bh = *(const us8*)&Hl[(16 * w + l15) * 136 + kc * 32 + g * 8];
      #pragma unroll
      for (int mb = 0; mb < 4; ++mb) {
        us8 a2 = *(const us8*)&W2l[((kc * 4 + mb) * 64 + l) * 8];
        c2[mb] = mfma16(a2, bh, c2[mb]);
      }
    }

    if (MODE == 1) {
      size_t e = e0 + 16 * w + l15;
      #pragma unroll
      for (int mb = 0; mb < 4; ++mb)
        *(uint2*)((unsigned short*)outv + e * 64 + 16 * mb + 4 * g) =
            pack4(c2[mb][0], c2[mb][1], c2[mb][2], c2[mb][3]);
    } else {
      #pragma unroll
      for (int mb = 0; mb < 4; ++mb)
        *(float4*)((float*)outv + (size_t)orig_h[hf] * 64 + 16 * mb + 4 * g) =
            (float4){c2[mb][0], c2[mb][1], c2[mb][2], c2[mb][3]};
    }
    if (hf == 0) __syncthreads();   // Hl reads done before half-1 overwrites
  }
}

// ---------------------------------------------------------------------------
// Node GEMM, K=128, optional per-block column-stat partials (NO atomics).
// MODE 0: U = [in0(f32,64)|in1(f32,64)]. MODE 1: U = relu(in0*sc+bi), in0 bf16[128].
template<int MODE, int OUTW, bool OUTBF, bool STATS>
__global__ __launch_bounds__(256) void node_mfma(
    const void* __restrict__ in0v, const float* __restrict__ in1,
    const float* __restrict__ sc, const float* __restrict__ bi,
    const unsigned short* __restrict__ WT, const float* __restrict__ B,
    void* __restrict__ yv, float* __restrict__ part) {
  __shared__ __align__(16) unsigned short Ul[64 * 136];
  const int t = threadIdx.x;
  const int w = t >> 6, l = t & 63, g = l >> 4, l15 = l & 15;
  const int r0 = blockIdx.x * 64;
  constexpr int NMB = OUTW / 64;

  {
    int r = t >> 2, q = t & 3;
    int row = r0 + r;
    int rr = row < NN ? row : NN - 1;
    unsigned short tmp[32];
    if (MODE == 0) {
      const float* base = (q < 2) ? (const float*)in0v : in1;
      const float4* p = (const float4*)(base + (size_t)rr * 64 + (q & 1) * 32);
      #pragma unroll
      for (int i = 0; i < 8; ++i) {
        float4 v = p[i];
        tmp[4*i+0] = f2bf(v.x); tmp[4*i+1] = f2bf(v.y);
        tmp[4*i+2] = f2bf(v.z); tmp[4*i+3] = f2bf(v.w);
      }
    } else {
      const unsigned short* srcp = (const unsigned short*)in0v + (size_t)rr * 128 + q * 32;
      #pragma unroll
      for (int i = 0; i < 4; ++i) {
        uint4 u = *(const uint4*)(srcp + i * 8);
        const unsigned short* us = (const unsigned short*)&u;
        #pragma unroll
        for (int j2 = 0; j2 < 2; ++j2) {
          int cb = q * 32 + i * 8 + j2 * 4;
          float4 s = *(const float4*)(sc + cb);
          float4 b = *(const float4*)(bi + cb);
          tmp[i*8+j2*4+0] = f2bf(fmaxf(bf2f(us[j2*4+0]) * s.x + b.x, 0.f));
          tmp[i*8+j2*4+1] = f2bf(fmaxf(bf2f(us[j2*4+1]) * s.y + b.y, 0.f));
          tmp[i*8+j2*4+2] = f2bf(fmaxf(bf2f(us[j2*4+2]) * s.z + b.z, 0.f));
          tmp[i*8+j2*4+3] = f2bf(fmaxf(bf2f(us[j2*4+3]) * s.w + b.w, 0.f));
        }
      }
    }
    unsigned short* ur = &Ul[r * 136 + q * 32];
    #pragma unroll
    for (int i = 0; i < 4; ++i)
      *(uint4*)&ur[i * 8] = *(uint4*)(tmp + i * 8);
  }

  __syncthreads();

  f4 c[NMB][4];
  #pragma unroll
  for (int mm = 0; mm < NMB; ++mm) {
    float4 bb = *(const float4*)(B + 16 * (NMB * w + mm) + 4 * g);
    #pragma unroll
    for (int nb = 0; nb < 4; ++nb)
      c[mm][nb] = (f4){bb.x, bb.y, bb.z, bb.w};
  }

  #pragma unroll
  for (int kc = 0; kc < 4; ++kc) {
    us8 bu[4];
    #pragma unroll
    for (int nb = 0; nb < 4; ++nb)
      bu[nb] = *(const us8*)&Ul[(16 * nb + l15) * 136 + kc * 32 + g * 8];
    #pragma unroll
    for (int mm = 0; mm < NMB; ++mm) {
      us8 a = *(const us8*)(WT + (size_t)(16 * (NMB * w + mm) + l15) * 128
                            + kc * 32 + g * 8);
      #pragma unroll
      for (int nb = 0; nb < 4; ++nb)
        c[mm][nb] = mfma16(a, bu[nb], c[mm][nb]);
    }
  }

  #pragma unroll
  for (int mm = 0; mm < NMB; ++mm)
    #pragma unroll
    for (int nb = 0; nb < 4; ++nb) {
      int row = r0 + l15 + 16 * nb;
      if (row < NN) {
        int f0 = 16 * (NMB * w + mm) + 4 * g;
        if (OUTBF) {
          *(uint2*)((unsigned short*)yv + (size_t)row * OUTW + f0) =
              pack4(c[mm][nb][0], c[mm][nb][1], c[mm][nb][2], c[mm][nb][3]);
        } else {
          *(float4*)((float*)yv + (size_t)row * OUTW + f0) =
              (float4){c[mm][nb][0], c[mm][nb][1], c[mm][nb][2], c[mm][nb][3]};
        }
      }
    }

  if (STATS) {
    float msk[4];
    #pragma unroll
    for (int nb = 0; nb < 4; ++nb)
      msk[nb] = (r0 + 16 * nb + l15 < NN) ? 1.f : 0.f;
    #pragma unroll
    for (int mm = 0; mm < NMB; ++mm) {
      float sv[4], qv[4];
      #pragma unroll
      for (int r = 0; r < 4; ++r) {
        float s = 0.f, q = 0.f;
        #pragma unroll
        for (int nb = 0; nb < 4; ++nb) {
          float v = c[mm][nb][r] * msk[nb];
          s += v; q += v * v;
        }
        #pragma unroll
        for (int d = 1; d < 16; d <<= 1) {
          s += __shfl_xor(s, d);
          q += __shfl_xor(q, d);
        }
        sv[r] = s; qv[r] = q;
      }
      if (l15 == 0) {
        int f0 = 16 * (NMB * w + mm) + 4 * g;
        *(float4*)&part[(size_t)blockIdx.x * 256 + f0] =
            (float4){sv[0], sv[1], sv[2], sv[3]};
        *(float4*)&part[(size_t)blockIdx.x * 256 + 128 + f0] =
            (float4){qv[0], qv[1], qv[2], qv[3]};
      }
    }
  }
}

// ---------------------------------------------------------------------------
// Last node layer (bn(y)->relu -> @h_w4 -> h_out f32) + fused QAB epilogue.
__global__ __launch_bounds__(256) void node_last_qab(
    const unsigned short* __restrict__ in0, const float* __restrict__ sc,
    const float* __restrict__ bi,
    const unsigned short* __restrict__ WT, const float* __restrict__ B,
    const unsigned short* __restrict__ WQ,
    float* __restrict__ hout, unsigned short* __restrict__ QAB) {
  __shared__ __align__(16) unsigned short Ul[64 * 136];
  const int t = threadIdx.x;
  const int w = t >> 6, l = t & 63, g = l >> 4, l15 = l & 15;
  const int r0 = blockIdx.x * 64;

  {
    int r = t >> 2, q = t & 3;
    int row = r0 + r;
    int rr = row < NN ? row : NN - 1;
    unsigned short tmp[32];
    const unsigned short* srcp = in0 + (size_t)rr * 128 + q * 32;
    #pragma unroll
    for (int i = 0; i < 4; ++i) {
      uint4 u = *(const uint4*)(srcp + i * 8);
      const unsigned short* us = (const unsigned short*)&u;
      #pragma unroll
      for (int j2 = 0; j2 < 2; ++j2) {
        int cb = q * 32 + i * 8 + j2 * 4;
        float4 s = *(const float4*)(sc + cb);
        float4 b = *(const float4*)(bi + cb);
        tmp[i*8+j2*4+0] = f2bf(fmaxf(bf2f(us[j2*4+0]) * s.x + b.x, 0.f));
        tmp[i*8+j2*4+1] = f2bf(fmaxf(bf2f(us[j2*4+1]) * s.y + b.y, 0.f));
        tmp[i*8+j2*4+2] = f2bf(fmaxf(bf2f(us[j2*4+2]) * s.z + b.z, 0.f));
        tmp[i*8+j2*4+3] = f2bf(fmaxf(bf2f(us[j2*4+3]) * s.w + b.w, 0.f));
      }
    }
    unsigned short* ur = &Ul[r * 136 + q * 32];
    #pragma unroll
    for (int i = 0; i < 4; ++i)
      *(uint4*)&ur[i * 8] = *(uint4*)(tmp + i * 8);
  }

  __syncthreads();

  f4 c[4];
  {
    float4 bb = *(const float4*)(B + 16 * w + 4 * g);
    #pragma unroll
    for (int nb = 0; nb < 4; ++nb)
      c[nb] = (f4){bb.x, bb.y, bb.z, bb.w};
  }
  #pragma unroll
  for (int kc = 0; kc < 4; ++kc) {
    us8 bu[4];
    #pragma unroll
    for (int nb = 0; nb < 4; ++nb)
      bu[nb] = *(const us8*)&Ul[(16 * nb + l15) * 136 + kc * 32 + g * 8];
    us8 a = *(const us8*)(WT + (size_t)(16 * w + l15) * 128 + kc * 32 + g * 8);
    #pragma unroll
    for (int nb = 0; nb < 4; ++nb)
      c[nb] = mfma16(a, bu[nb], c[nb]);
  }

  #pragma unroll
  for (int nb = 0; nb < 4; ++nb) {
    int row = r0 + l15 + 16 * nb;
    if (row < NN) {
      int f0 = 16 * w + 4 * g;
      *(float4*)(hout + (size_t)row * 64 + f0) =
          (float4){c[nb][0], c[nb][1], c[nb][2], c[nb][3]};
    }
  }

  // ---- QAB epilogue: relu(h_out) @ WQ^T, swizzled out
  __syncthreads();   // everyone done reading Ul
  #pragma unroll
  for (int nb = 0; nb < 4; ++nb) {
    *(uint2*)&Ul[(16 * nb + l15) * 72 + 16 * w + 4 * g] =
        pack4(fmaxf(c[nb][0], 0.f), fmaxf(c[nb][1], 0.f),
              fmaxf(c[nb][2], 0.f), fmaxf(c[nb][3], 0.f));
  }
  us8 aq[4][2];
  #pragma unroll
  for (int mm = 0; mm < 4; ++mm)
    #pragma unroll
    for (int kc = 0; kc < 2; ++kc)
      aq[mm][kc] = *(const us8*)(WQ + (size_t)(64 * w + 16 * mm + l15) * 64 + kc * 32 + g * 8);
  __syncthreads();

  f4 cq[4][4];
  #pragma unroll
  for (int mm = 0; mm < 4; ++mm)
    #pragma unroll
    for (int nb = 0; nb < 4; ++nb)
      cq[mm][nb] = (f4){0.f, 0.f, 0.f, 0.f};
  #pragma unroll
  for (int kc = 0; kc < 2; ++kc) {
    us8 bz[4];
    #pragma unroll
    for (int nb = 0; nb < 4; ++nb)
      bz[nb] = *(const us8*)&Ul[(16 * nb + l15) * 72 + kc * 32 + g * 8];
    #pragma unroll
    for (int mm = 0; mm < 4; ++mm)
      #pragma unroll
      for (int nb = 0; nb < 4; ++nb)
        cq[mm][nb] = mfma16(aq[mm][kc], bz[nb], cq[mm][nb]);
  }
  #pragma unroll
  for (int mm = 0; mm < 4; ++mm)
    #pragma unroll
    for (int nb = 0; nb < 4; ++nb) {
      int row = r0 + 16 * nb + l15;
      if (row < NN) {
        int f0 = 64 * w + 16 * mm + 4 * g;
        int half = f0 >> 7;
        int f1 = f0 & 127;
        int pos = half * 128 + ((f1 >> 5) << 5) + (((f1 & 15) >> 2) << 3) + (((f1 >> 4) & 1) << 2);
        *(uint2*)(QAB + (size_t)row * 256 + pos) =
            pack4(cq[mm][nb][0], cq[mm][nb][1], cq[mm][nb][2], cq[mm][nb][3]);
      }
    }
}

// ---------------------------------------------------------------------------
// Per-node online scatter-softmax over CSR-contiguous m rows (bf16).
// Four independent online states (4 loads in flight), merged at the end.
__global__ void node_softmax(const unsigned short* __restrict__ m,
                             const int* __restrict__ off,
                             const float* __restrict__ tptr,
                             float* __restrict__ msg) {
  int gw = (blockIdx.x * 256 + threadIdx.x) >> 6;
  int lane = threadIdx.x & 63;
  if (gw >= NN) return;
  float t = tptr[0];
  int beg = off[gw], end = off[gw + 1];
  int len = end - beg;
  float M[4] = {-3e38f, -3e38f, -3e38f, -3e38f};
  float S[4] = {0.f, 0.f, 0.f, 0.f};
  float W[4] = {0.f, 0.f, 0.f, 0.f};
  int i = beg;
  for (; i + 3 < end; i += 4) {
    float v0 = bf2f(m[(size_t)(i + 0) * 64 + lane]);
    float v1 = bf2f(m[(size_t)(i + 1) * 64 + lane]);
    float v2 = bf2f(m[(size_t)(i + 2) * 64 + lane]);
    float v3 = bf2f(m[(size_t)(i + 3) * 64 + lane]);
    float s0 = v0 * t, s1 = v1 * t, s2 = v2 * t, s3 = v3 * t;
    float M0 = fmaxf(M[0], s0), M1 = fmaxf(M[1], s1);
    float M2 = fmaxf(M[2], s2), M3 = fmaxf(M[3], s3);
    float c0 = __expf(M[0] - M0), c1 = __expf(M[1] - M1);
    float c2 = __expf(M[2] - M2), c3 = __expf(M[3] - M3);
    float p0 = __expf(s0 - M0), p1 = __expf(s1 - M1);
    float p2 = __expf(s2 - M2), p3 = __expf(s3 - M3);
    S[0] = S[0] * c0 + p0;  W[0] = W[0] * c0 + v0 * p0;  M[0] = M0;
    S[1] = S[1] * c1 + p1;  W[1] = W[1] * c1 + v1 * p1;  M[1] = M1;
    S[2] = S[2] * c2 + p2;  W[2] = W[2] * c2 + v2 * p2;  M[2] = M2;
    S[3] = S[3] * c3 + p3;  W[3] = W[3] * c3 + v3 * p3;  M[3] = M3;
  }
  for (; i < end; ++i) {
    float v0 = bf2f(m[(size_t)i * 64 + lane]);
    float s0 = v0 * t;
    float M0 = fmaxf(M[0], s0);
    float c0 = __expf(M[0] - M0);
    float p0 = __expf(s0 - M0);
    S[0] = S[0] * c0 + p0;  W[0] = W[0] * c0 + v0 * p0;  M[0] = M0;
  }
  float Mn = fmaxf(fmaxf(M[0], M[1]), fmaxf(M[2], M[3]));
  float Sm = 0.f, Wm = 0.f;
  #pragma unroll
  for (int k = 0; k < 4; ++k) {
    float ck = __expf(M[k] - Mn);
    Sm += S[k] * ck;
    Wm += W[k] * ck;
  }
  msg[(size_t)gw * 64 + lane] = (len > 0) ? (Wm / Sm) : 0.f;
}

// ---------------------------------------------------------------------------
extern "C" void kernel_launch(void* const* d_in, const int* in_sizes, int n_in,
                              void* d_out, int out_size, void* d_ws, size_t ws_size,
                              hipStream_t stream) {
  const float* x     = (const float*)d_in[0];
  const int*   ei    = (const int*)d_in[1];
  const float* ea    = (const float*)d_in[2];
  const float* gh_w  = (const float*)d_in[3];
  const float* gh_b  = (const float*)d_in[4];
  const float* gv_w  = (const float*)d_in[5];
  const float* gv_b  = (const float*)d_in[6];
  const float* tpar  = (const float*)d_in[7];
  const float* p_w1  = (const float*)d_in[8];
  const float* p_b1  = (const float*)d_in[9];
  const float* p_w2  = (const float*)d_in[10];
  const float* p_b2  = (const float*)d_in[11];
  const float* h_w1  = (const float*)d_in[12];
  const float* h_b1  = (const float*)d_in[13];
  const float* h_g1  = (const float*)d_in[14];
  const float* h_bb1 = (const float*)d_in[15];
  const float* h_w2  = (const float*)d_in[16];
  const float* h_b2  = (const float*)d_in[17];
  const float* h_g2  = (const float*)d_in[18];
  const float* h_bb2 = (const float*)d_in[19];
  const float* h_w3  = (const float*)d_in[20];
  const float* h_b3  = (const float*)d_in[21];
  const float* h_g3  = (const float*)d_in[22];
  const float* h_bb3 = (const float*)d_in[23];
  const float* h_w4  = (const float*)d_in[24];
  const float* h_b4  = (const float*)d_in[25];
  const float* e_w1  = (const float*)d_in[26];
  const float* e_b1  = (const float*)d_in[27];
  const float* e_w2  = (const float*)d_in[28];
  const float* e_b2  = (const float*)d_in[29];

  float* h_out = (float*)d_out;
  float* v_out = (float*)d_out + (size_t)NN * 64;

  const int* src = ei;
  const int* dst = ei + NE;

  char* w = (char*)d_ws;
  int* cnt = (int*)w;                       // 200704 B, zeroed
  size_t zero_bytes = 200704;

  char* p = w + zero_bytes;
  float* sb = (float*)p; p += 4096;
  float* sbx_s = sb,       *sbx_b = sb + 64;
  float* sbv_s = sb + 128, *sbv_b = sb + 192;
  float* sb1_s = sb + 256, *sb1_b = sb + 384;
  float* sb2_s = sb + 512, *sb2_b = sb + 640;
  float* sb3_s = sb + 768, *sb3_b = sb + 896;
  float* pstat = (float*)p; p += 1280 * 128 * 4;
  float* npart = (float*)p; p += 782 * 256 * 4;
  int* bsum   = (int*)p; p += 1024;
  int* off    = (int*)p; p += 200704;
  int* rank   = (int*)p; p += (size_t)NE * 4;
  int* einv   = (int*)p; p += (size_t)NE * 4;
  int* src_s  = (int*)p; p += (size_t)NE * 4;
  int* dst_s  = (int*)p; p += (size_t)NE * 4;
  float* h    = (float*)p; p += (size_t)NN * 64 * 4;
  float* msg  = (float*)p; p += (size_t)NN * 64 * 4;
  unsigned short* vbf  = (unsigned short*)p; p += (size_t)NE * 64 * 2;
  unsigned short* m_bf = (unsigned short*)p; p += (size_t)NE * 64 * 2;
  unsigned short* PAB  = (unsigned short*)p; p += (size_t)NN * 256 * 2;
  unsigned short* QAB  = (unsigned short*)p; p += (size_t)NN * 256 * 2;
  unsigned short* y1   = (unsigned short*)p; p += (size_t)NN * 128 * 2;
  unsigned short* y2   = (unsigned short*)p; p += (size_t)NN * 128 * 2;
  unsigned short* wpab  = (unsigned short*)p; p += 256 * 64 * 2;
  unsigned short* wqab  = (unsigned short*)p; p += 256 * 64 * 2;
  unsigned short* w1c_p = (unsigned short*)p; p += 128 * 64 * 2;
  unsigned short* w1c_e = (unsigned short*)p; p += 128 * 64 * 2;
  unsigned short* w2f_p = (unsigned short*)p; p += 64 * 128 * 2;
  unsigned short* w2f_e = (unsigned short*)p; p += 64 * 128 * 2;
  unsigned short* h_w1t = (unsigned short*)p; p += 128 * 128 * 2;
  unsigned short* h_w2t = (unsigned short*)p; p += 128 * 128 * 2;
  unsigned short* h_w3t = (unsigned short*)p; p += 128 * 128 * 2;
  unsigned short* h_w4t = (unsigned short*)p; p += 64 * 128 * 2;

  hipMemsetAsync(d_ws, 0, zero_bytes, stream);

  wprep<<<480, 256, 0, stream>>>(p_w1, e_w1, p_w2, e_w2, h_w1, h_w2, h_w3, h_w4,
                                 wpab, wqab, w1c_p, w1c_e, w2f_p, w2f_e,
                                 h_w1t, h_w2t, h_w3t, h_w4t);

  // fused: BN stat partials + CSR count/rank (overlapped in one grid)
  prep_all<<<4405, 256, 0, stream>>>(x, ea, dst, pstat, cnt, rank);

  // hierarchical scan
  scan_part<<<196, 256, 0, stream>>>(cnt, bsum);
  scan_top<<<1, 256, 0, stream>>>(bsum);
  scan_add<<<196, 256, 0, stream>>>(cnt, bsum, off);

  reduce_stats<<<2, 1024, 0, stream>>>(pstat, gh_w, gh_b, gv_w, gv_b, sb);

  // CSR pass 2: atomic-free placement + fused BN scatter of edge_attr
  scatter_all<<<3125, 256, 0, stream>>>(ea, sbv_s, sbv_b, src, dst, off, rank,
                                        src_s, dst_s, einv, vbf);

  // node-side factor: PAB = relu(bn(x)) @ [pW1a|pW1b]; also writes h
  pab_gemm<<<782, 256, 0, stream>>>(x, sbx_s, sbx_b, wpab, PAB, h);

  // message MLP (CSR order): table0 = dst (pW1a), table1 = src (pW1b)
  edge_mlp6<1><<<6250, 256, 0, stream>>>(vbf, PAB, dst_s, src_s, einv,
                                         w1c_p, p_b1, w2f_p, p_b2, (void*)m_bf);

  node_softmax<<<12500, 256, 0, stream>>>(m_bf, off, tpar, msg);

  // node MLP chain: per-block stat partials + tiny reduce (no atomics)
  node_mfma<0, 128, true, true><<<782, 256, 0, stream>>>(
      h, msg, nullptr, nullptr, h_w1t, h_b1, (void*)y1, npart);
  reduce_sb<<<1, 1024, 0, stream>>>(npart, h_g1, h_bb1, sb1_s, sb1_b);

  node_mfma<1, 128, true, true><<<782, 256, 0, stream>>>(
      y1, nullptr, sb1_s, sb1_b, h_w2t, h_b2, (void*)y2, npart);
  reduce_sb<<<1, 1024, 0, stream>>>(npart, h_g2, h_bb2, sb2_s, sb2_b);

  node_mfma<1, 128, true, true><<<782, 256, 0, stream>>>(
      y2, nullptr, sb2_s, sb2_b, h_w3t, h_b3, (void*)y1, npart);
  reduce_sb<<<1, 1024, 0, stream>>>(npart, h_g3, h_bb3, sb3_s, sb3_b);

  // last layer + fused QAB = relu(h_out) @ [eW1a|eW1b]
  node_last_qab<<<782, 256, 0, stream>>>(y1, sb3_s, sb3_b, h_w4t, h_b4, wqab,
                                         h_out, QAB);

  // edge output MLP (CSR order): table0 = src (eW1a), table1 = dst (eW1b)
  edge_mlp6<2><<<6250, 256, 0, stream>>>(vbf, QAB, src_s, dst_s, einv,
                                         w1c_e, e_b1, w2f_e, e_b2, (void*)v_out);
}

// Round 13
// 735.720 us; speedup vs baseline: 1.2297x; 1.0887x over previous
//
#include <hip/hip_runtime.h>
#include <math.h>

#define NN 50000
#define NE 800000

typedef __attribute__((ext_vector_type(8))) unsigned short us8;
typedef __attribute__((ext_vector_type(8))) __bf16 bf8;
typedef __attribute__((ext_vector_type(4))) float f4;

__device__ __forceinline__ unsigned short f2bf(float f) {
  unsigned int u = __float_as_uint(f);
  unsigned int r = u + 0x7FFFu + ((u >> 16) & 1u);
  return (unsigned short)(r >> 16);
}
__device__ __forceinline__ float bf2f(unsigned short h) {
  return __uint_as_float(((unsigned int)h) << 16);
}
__device__ __forceinline__ f4 mfma16(us8 a, us8 b, f4 c) {
  return __builtin_amdgcn_mfma_f32_16x16x32_bf16(
      __builtin_bit_cast(bf8, a), __builtin_bit_cast(bf8, b), c, 0, 0, 0);
}
__device__ __forceinline__ uint2 pack4(float a, float b, float c, float d) {
  uint2 r;
  r.x = (unsigned)f2bf(a) | ((unsigned)f2bf(b) << 16);
  r.y = (unsigned)f2bf(c) | ((unsigned)f2bf(d) << 16);
  return r;
}

// ---------------------------------------------------------------------------
// Fused prep: blocks [0,256) = x stats, [256,1280) = ea stats (per-block
// partials, no atomics), [1280,4405) = CSR count+rank (one atomic pass).
__global__ void prep_all(const float* __restrict__ x, const float* __restrict__ ea,
                         const int* __restrict__ dst,
                         float* __restrict__ pstat, int* __restrict__ cnt,
                         int* __restrict__ rank) {
  int b = blockIdx.x;
  int t = threadIdx.x;
  if (b >= 1280) {                 // count + rank
    int e = (b - 1280) * 256 + t;
    rank[e] = atomicAdd(&cnt[dst[e]], 1);
    return;
  }
  const float* srcp; int rows; int nblk, b0;
  if (b < 256) { srcp = x;  rows = NN; nblk = 256;  b0 = b; }
  else         { srcp = ea; rows = NE; nblk = 1024; b0 = b - 256; }
  int cg = (t & 15) * 4;           // column group (4 cols)
  int rs = t >> 4;                 // row slot 0..15
  float4 s = {0.f, 0.f, 0.f, 0.f}, q = {0.f, 0.f, 0.f, 0.f};
  for (int r = b0 * 64 + rs; r < rows; r += nblk * 64) {
    #pragma unroll
    for (int u = 0; u < 4; ++u) {
      int rr = r + u * 16;
      if (rr < rows) {
        float4 v = *(const float4*)(srcp + (size_t)rr * 64 + cg);
        s.x += v.x; s.y += v.y; s.z += v.z; s.w += v.w;
        q.x += v.x * v.x; q.y += v.y * v.y; q.z += v.z * v.z; q.w += v.w * v.w;
      }
    }
  }
  __shared__ float4 ls[256], lq[256];
  ls[t] = s; lq[t] = q;
  __syncthreads();
  if (rs == 0) {
    #pragma unroll
    for (int i = 1; i < 16; ++i) {
      float4 a = ls[i * 16 + t], z = lq[i * 16 + t];
      s.x += a.x; s.y += a.y; s.z += a.z; s.w += a.w;
      q.x += z.x; q.y += z.y; q.z += z.z; q.w += z.w;
    }
    *(float4*)&pstat[(size_t)b * 128 + cg] = s;
    *(float4*)&pstat[(size_t)b * 128 + 64 + cg] = q;
  }
}

// BN stats pass 2: reduce partials -> scale/bias. block 0 = x, block 1 = ea.
__global__ void reduce_stats(const float* __restrict__ pstat,
                             const float* __restrict__ gh_w, const float* __restrict__ gh_b,
                             const float* __restrict__ gv_w, const float* __restrict__ gv_b,
                             float* __restrict__ sb) {
  int t = threadIdx.x;             // 1024
  int col = t & 63, slot = t >> 6; // 16 slots
  int base = blockIdx.x ? 256 : 0;
  int n = blockIdx.x ? 1024 : 256;
  float s = 0.f, q = 0.f;
  for (int r = slot; r < n; r += 16) {
    s += pstat[(size_t)(base + r) * 128 + col];
    q += pstat[(size_t)(base + r) * 128 + 64 + col];
  }
  __shared__ float ls[1024], lq[1024];
  ls[t] = s; lq[t] = q;
  __syncthreads();
  if (slot == 0) {
    #pragma unroll
    for (int i = 1; i < 16; ++i) { s += ls[i * 64 + col]; q += lq[i * 64 + col]; }
    float inv = blockIdx.x ? (1.0f / NE) : (1.0f / NN);
    const float* gp = blockIdx.x ? gv_w : gh_w;
    const float* bp = blockIdx.x ? gv_b : gh_b;
    float mu = s * inv;
    float var = q * inv - mu * mu;
    float sc = gp[col] * rsqrtf(var + 1e-5f);
    int o = blockIdx.x ? 128 : 0;
    sb[o + col] = sc;
    sb[o + 64 + col] = bp[col] - mu * sc;
  }
}

// Node-layer BN: reduce per-block partials (782 x 256) -> scale/bias (128 cols)
__global__ void reduce_sb(const float* __restrict__ part,
                          const float* __restrict__ g, const float* __restrict__ b,
                          float* __restrict__ scale, float* __restrict__ bias) {
  int t = threadIdx.x;             // 1024
  int col = t & 127, slot = t >> 7; // 8 slots
  float s = 0.f, q = 0.f;
  for (int r = slot; r < 782; r += 8) {
    s += part[(size_t)r * 256 + col];
    q += part[(size_t)r * 256 + 128 + col];
  }
  __shared__ float ls[1024], lq[1024];
  ls[t] = s; lq[t] = q;
  __syncthreads();
  if (slot == 0) {
    #pragma unroll
    for (int i = 1; i < 8; ++i) { s += ls[i * 128 + col]; q += lq[i * 128 + col]; }
    float mu = s * (1.0f / NN);
    float var = q * (1.0f / NN) - mu * mu;
    float sc = g[col] * rsqrtf(var + 1e-5f);
    scale[col] = sc;
    bias[col] = b[col] - mu * sc;
  }
}

// ---------------------------------------------------------------------------
// Fused weight prep.
__global__ void wprep(const float* __restrict__ p_w1, const float* __restrict__ e_w1,
                      const float* __restrict__ p_w2, const float* __restrict__ e_w2,
                      const float* __restrict__ h_w1, const float* __restrict__ h_w2,
                      const float* __restrict__ h_w3, const float* __restrict__ h_w4,
                      unsigned short* __restrict__ wpab, unsigned short* __restrict__ wqab,
                      unsigned short* __restrict__ w1c_p, unsigned short* __restrict__ w1c_e,
                      unsigned short* __restrict__ w2f_p, unsigned short* __restrict__ w2f_e,
                      unsigned short* __restrict__ hw1t, unsigned short* __restrict__ hw2t,
                      unsigned short* __restrict__ hw3t, unsigned short* __restrict__ hw4t) {
  int gi = blockIdx.x * 256 + threadIdx.x;
  if (gi < 32768) {                        // wpab / wqab [256][64]
    const float* w = (gi < 16384) ? p_w1 : e_w1;
    unsigned short* o = (gi < 16384) ? wpab : wqab;
    int i = gi & 16383;
    int f = i >> 6, k = i & 63;
    int srcrow = k + ((f >> 7) << 6);
    o[i] = f2bf(w[(size_t)srcrow * 128 + (f & 127)]);
  } else if (gi < 49152) {                 // w1c_p / w1c_e [128][64]
    int i = (gi - 32768) & 8191;
    const float* w = (gi < 40960) ? (p_w1 + 128 * 128) : (e_w1 + 128 * 128);
    unsigned short* o = (gi < 40960) ? w1c_p : w1c_e;
    int f = i >> 6, k = i & 63;
    o[i] = f2bf(w[(size_t)k * 128 + f]);
  } else if (gi < 65536) {                 // w2f fragment-linear [kc][mb][lane][8]
    int i = (gi - 49152) & 8191;
    const float* w = (gi < 57344) ? p_w2 : e_w2;
    unsigned short* o = (gi < 57344) ? w2f_p : w2f_e;
    int j = i & 7, lane = (i >> 3) & 63, frag = i >> 9;
    int kc = frag >> 2, mb = frag & 3;
    int l15 = lane & 15, g = lane >> 4;
    o[i] = f2bf(w[(size_t)(kc * 32 + g * 8 + j) * 64 + 16 * mb + l15]);
  } else if (gi < 114688) {                // hw1t/hw2t/hw3t [128][128]
    int seg = (gi - 65536) >> 14;
    int i = (gi - 65536) & 16383;
    const float* w = (seg == 0) ? h_w1 : (seg == 1) ? h_w2 : h_w3;
    unsigned short* o = (seg == 0) ? hw1t : (seg == 1) ? hw2t : hw3t;
    int n = i >> 7, k = i & 127;
    o[i] = f2bf(w[(size_t)k * 128 + n]);
  } else if (gi < 122880) {                // hw4t [64][128]
    int i = gi - 114688;
    int n = i >> 7, k = i & 127;
    hw4t[i] = f2bf(h_w4[(size_t)k * 64 + n]);
  }
}

// ---------------------------------------------------------------------------
// hierarchical scan
__global__ void scan_part(const int* __restrict__ cnt, int* __restrict__ bsum) {
  __shared__ int ls[256];
  int i = blockIdx.x * 256 + threadIdx.x;
  ls[threadIdx.x] = (i < NN) ? cnt[i] : 0;
  __syncthreads();
  for (int d = 128; d > 0; d >>= 1) {
    if (threadIdx.x < d) ls[threadIdx.x] += ls[threadIdx.x + d];
    __syncthreads();
  }
  if (threadIdx.x == 0) bsum[blockIdx.x] = ls[0];
}

__global__ void scan_top(int* __restrict__ bsum) {
  __shared__ int ps[256];
  int t = threadIdx.x;
  int v = (t < 196) ? bsum[t] : 0;
  ps[t] = v;
  __syncthreads();
  for (int d = 1; d < 256; d <<= 1) {
    int tv = (t >= d) ? ps[t - d] : 0;
    __syncthreads();
    ps[t] += tv;
    __syncthreads();
  }
  if (t < 196) bsum[t] = ps[t] - v;   // exclusive
}

__global__ void scan_add(const int* __restrict__ cnt, const int* __restrict__ bsum,
                         int* __restrict__ off) {
  __shared__ int ps[256];
  int t = threadIdx.x;
  int i = blockIdx.x * 256 + t;
  int v = (i < NN) ? cnt[i] : 0;
  ps[t] = v;
  __syncthreads();
  for (int d = 1; d < 256; d <<= 1) {
    int tv = (t >= d) ? ps[t - d] : 0;
    __syncthreads();
    ps[t] += tv;
    __syncthreads();
  }
  if (i < NN) off[i] = bsum[blockIdx.x] + ps[t] - v;
  if (blockIdx.x == 0 && t == 0) off[NN] = NE;
}

// ---------------------------------------------------------------------------
// CSR pass 2: placement via off[dst]+rank (NO atomics) + fused BN scatter.
__global__ void scatter_all(const float* __restrict__ ea, const float* __restrict__ sc,
                            const float* __restrict__ bi,
                            const int* __restrict__ srca, const int* __restrict__ dsta,
                            const int* __restrict__ off, const int* __restrict__ rank,
                            int* __restrict__ src_s, int* __restrict__ dst_s,
                            int* __restrict__ einv, unsigned short* __restrict__ vbf) {
  __shared__ int posl[256];
  int t = threadIdx.x;
  int e0 = blockIdx.x * 256;
  int e = e0 + t;
  int n = dsta[e];
  int pos = off[n] + rank[e];
  posl[t] = pos;
  src_s[pos] = srca[e];
  dst_s[pos] = n;
  einv[pos] = e;
  __syncthreads();
  #pragma unroll
  for (int it = 0; it < 8; ++it) {
    int task = it * 256 + t;
    int r = task >> 3, q = task & 7;
    int c8 = q * 8;
    const float4* px = (const float4*)(ea + (size_t)(e0 + r) * 64 + c8);
    float4 a = px[0], b2 = px[1];
    float4 s0 = *(const float4*)(sc + c8), s1 = *(const float4*)(sc + c8 + 4);
    float4 b0 = *(const float4*)(bi + c8),  b1 = *(const float4*)(bi + c8 + 4);
    unsigned short tmp[8];
    tmp[0] = f2bf(fmaxf(a.x * s0.x + b0.x, 0.f));
    tmp[1] = f2bf(fmaxf(a.y * s0.y + b0.y, 0.f));
    tmp[2] = f2bf(fmaxf(a.z * s0.z + b0.z, 0.f));
    tmp[3] = f2bf(fmaxf(a.w * s0.w + b0.w, 0.f));
    tmp[4] = f2bf(fmaxf(b2.x * s1.x + b1.x, 0.f));
    tmp[5] = f2bf(fmaxf(b2.y * s1.y + b1.y, 0.f));
    tmp[6] = f2bf(fmaxf(b2.z * s1.z + b1.z, 0.f));
    tmp[7] = f2bf(fmaxf(b2.w * s1.w + b1.w, 0.f));
    *(uint4*)(vbf + (size_t)posl[r] * 64 + c8) = *(uint4*)tmp;
  }
}

// ---------------------------------------------------------------------------
// PAB = bf16( relu(bn(in)) @ WT^T ), gather-swizzled out; also writes h (f32).
__global__ __launch_bounds__(256) void pab_gemm(
    const float* __restrict__ in, const float* __restrict__ sc,
    const float* __restrict__ bi, const unsigned short* __restrict__ WT,
    unsigned short* __restrict__ out, float* __restrict__ hout) {
  __shared__ __align__(16) unsigned short Ul[64 * 72];
  const int t = threadIdx.x;
  const int w = t >> 6, l = t & 63, g = l >> 4, l15 = l & 15;
  const int r0 = blockIdx.x * 64;

  #pragma unroll
  for (int it = 0; it < 2; ++it) {
    int idx = it * 256 + t;
    int r = idx >> 3, q = idx & 7;
    int row = r0 + r; int rr = row < NN ? row : NN - 1;
    float4 v = *(const float4*)(in + (size_t)rr * 64 + q * 8);
    float4 v2 = *(const float4*)(in + (size_t)rr * 64 + q * 8 + 4);
    float4 s0 = *(const float4*)(sc + q * 8), s1 = *(const float4*)(sc + q * 8 + 4);
    float4 c0 = *(const float4*)(bi + q * 8), c1 = *(const float4*)(bi + q * 8 + 4);
    v.x = fmaxf(v.x * s0.x + c0.x, 0.f);   v.y = fmaxf(v.y * s0.y + c0.y, 0.f);
    v.z = fmaxf(v.z * s0.z + c0.z, 0.f);   v.w = fmaxf(v.w * s0.w + c0.w, 0.f);
    v2.x = fmaxf(v2.x * s1.x + c1.x, 0.f); v2.y = fmaxf(v2.y * s1.y + c1.y, 0.f);
    v2.z = fmaxf(v2.z * s1.z + c1.z, 0.f); v2.w = fmaxf(v2.w * s1.w + c1.w, 0.f);
    unsigned short tmp[8];
    tmp[0] = f2bf(v.x);  tmp[1] = f2bf(v.y);  tmp[2] = f2bf(v.z);  tmp[3] = f2bf(v.w);
    tmp[4] = f2bf(v2.x); tmp[5] = f2bf(v2.y); tmp[6] = f2bf(v2.z); tmp[7] = f2bf(v2.w);
    *(uint4*)&Ul[r * 72 + q * 8] = *(uint4*)tmp;
    if (row < NN) {
      *(float4*)(hout + (size_t)row * 64 + q * 8) = v;
      *(float4*)(hout + (size_t)row * 64 + q * 8 + 4) = v2;
    }
  }
  us8 a[4][2];
  #pragma unroll
  for (int mm = 0; mm < 4; ++mm)
    #pragma unroll
    for (int kc = 0; kc < 2; ++kc)
      a[mm][kc] = *(const us8*)(WT + (size_t)(64 * w + 16 * mm + l15) * 64 + kc * 32 + g * 8);
  __syncthreads();

  f4 c[4][4];
  #pragma unroll
  for (int mm = 0; mm < 4; ++mm)
    #pragma unroll
    for (int nb = 0; nb < 4; ++nb)
      c[mm][nb] = (f4){0.f, 0.f, 0.f, 0.f};
  #pragma unroll
  for (int kc = 0; kc < 2; ++kc) {
    us8 bz[4];
    #pragma unroll
    for (int nb = 0; nb < 4; ++nb)
      bz[nb] = *(const us8*)&Ul[(16 * nb + l15) * 72 + kc * 32 + g * 8];
    #pragma unroll
    for (int mm = 0; mm < 4; ++mm)
      #pragma unroll
      for (int nb = 0; nb < 4; ++nb)
        c[mm][nb] = mfma16(a[mm][kc], bz[nb], c[mm][nb]);
  }
  #pragma unroll
  for (int mm = 0; mm < 4; ++mm)
    #pragma unroll
    for (int nb = 0; nb < 4; ++nb) {
      int row = r0 + 16 * nb + l15;
      if (row < NN) {
        int f0 = 64 * w + 16 * mm + 4 * g;
        int half = f0 >> 7;
        int f1 = f0 & 127;
        int pos = half * 128 + ((f1 >> 5) << 5) + (((f1 & 15) >> 2) << 3) + (((f1 >> 4) & 1) << 2);
        *(uint2*)(out + (size_t)row * 256 + pos) =
            pack4(c[mm][nb][0], c[mm][nb][1], c[mm][nb][2], c[mm][nb][3]);
      }
    }
}

// ---------------------------------------------------------------------------
// Edge MLP v7: exact v4 structure, but W2 fragments read directly from global
// (W2F is 16KB, L1-resident per CU) instead of an LDS stage. LDS = Hl only
// (17.4KB) -> 8 blocks/CU instead of 4.
// MODE 1: m (bf16) contiguous out. MODE 2: v_out (f32) scatter via einv.
template<int MODE>
__global__ __launch_bounds__(256, 4) void edge_mlp7(
    const unsigned short* __restrict__ vbf,     // CSR-order rows
    const unsigned short* __restrict__ AB,      // swizzled PAB/QAB
    const int* __restrict__ idx0, const int* __restrict__ idx1,
    const int* __restrict__ einv,
    const unsigned short* __restrict__ W1cT, const float* __restrict__ B1,
    const unsigned short* __restrict__ W2F, const float* __restrict__ B2,
    void* __restrict__ outv) {
  __shared__ __align__(16) unsigned short Hl[64 * 136];
  const int t = threadIdx.x;
  const int w = t >> 6, l = t & 63, g = l >> 4, l15 = l & 15;
  int bid = blockIdx.x;
  {  // bijective XCD-chunked swizzle (nwg=12500, 8 XCDs)
    const int q = 12500 / 8, r = 12500 % 8;
    int x = bid % 8, j = bid / 8;
    bid = (x < r ? x * (q + 1) : r * (q + 1) + (x - r) * q) + j;
  }
  const size_t e0 = (size_t)bid * 64;

  // ---- phase 0: gathers, W1c frags, einv
  uint4 ga0[4], ga1[4];
  #pragma unroll
  for (int nb = 0; nb < 4; ++nb) {
    size_t e = e0 + 16 * nb + l15;
    int n0 = idx0[e], n1 = idx1[e];
    ga0[nb] = *(const uint4*)(AB + (size_t)n0 * 256 + w * 32 + g * 8);
    ga1[nb] = *(const uint4*)(AB + (size_t)n1 * 256 + 128 + w * 32 + g * 8);
  }
  int orig = 0;
  if (MODE == 2) orig = einv[e0 + 16 * w + l15];
  us8 a1[2][2];
  #pragma unroll
  for (int mm = 0; mm < 2; ++mm)
    #pragma unroll
    for (int kc = 0; kc < 2; ++kc)
      a1[mm][kc] = *(const us8*)(W1cT + (size_t)(32 * w + 16 * mm + l15) * 64
                                 + kc * 32 + g * 8);

  // ---- phase 1: layer 1 MFMA, V directly from global (rows contiguous)
  f4 c1[2][4];
  #pragma unroll
  for (int mm = 0; mm < 2; ++mm)
    #pragma unroll
    for (int nb = 0; nb < 4; ++nb)
      c1[mm][nb] = (f4){0.f, 0.f, 0.f, 0.f};
  #pragma unroll
  for (int kc = 0; kc < 2; ++kc) {
    us8 bz[4];
    #pragma unroll
    for (int nb = 0; nb < 4; ++nb)
      bz[nb] = *(const us8*)(vbf + (e0 + 16 * nb + l15) * 64 + kc * 32 + g * 8);
    #pragma unroll
    for (int mm = 0; mm < 2; ++mm)
      #pragma unroll
      for (int nb = 0; nb < 4; ++nb)
        c1[mm][nb] = mfma16(a1[mm][kc], bz[nb], c1[mm][nb]);
  }

  // ---- phase 2: H = relu(c1 + B1 + ga0 + ga1) -> Hl (bf16)
  #pragma unroll
  for (int mm = 0; mm < 2; ++mm) {
    float4 bb = *(const float4*)(B1 + 32 * w + 16 * mm + 4 * g);
    #pragma unroll
    for (int nb = 0; nb < 4; ++nb) {
      f4 v = c1[mm][nb];
      unsigned int ux = mm ? ga0[nb].z : ga0[nb].x;
      unsigned int uy = mm ? ga0[nb].w : ga0[nb].y;
      unsigned int vx = mm ? ga1[nb].z : ga1[nb].x;
      unsigned int vy = mm ? ga1[nb].w : ga1[nb].y;
      float h0 = v[0] + bb.x + bf2f((unsigned short)(ux & 0xffff))
                             + bf2f((unsigned short)(vx & 0xffff));
      float h1 = v[1] + bb.y + bf2f((unsigned short)(ux >> 16))
                             + bf2f((unsigned short)(vx >> 16));
      float h2 = v[2] + bb.z + bf2f((unsigned short)(uy & 0xffff))
                             + bf2f((unsigned short)(vy & 0xffff));
      float h3 = v[3] + bb.w + bf2f((unsigned short)(uy >> 16))
                             + bf2f((unsigned short)(vy >> 16));
      int er = 16 * nb + l15;
      *(uint2*)&Hl[er * 136 + 32 * w + 16 * mm + 4 * g] =
          pack4(fmaxf(h0, 0.f), fmaxf(h1, 0.f), fmaxf(h2, 0.f), fmaxf(h3, 0.f));
    }
  }
  __syncthreads();   // Hl ready

  // ---- phase 3: layer 2 (D2^T = W2^T * H^T), W2 frags from global (L1-hot)
  f4 c2[4];
  #pragma unroll
  for (int mb = 0; mb < 4; ++mb) {
    float4 bb = *(const float4*)(B2 + 16 * mb + 4 * g);
    c2[mb] = (f4){bb.x, bb.y, bb.z, bb.w};
  }
  #pragma unroll
  for (int kc = 0; kc < 4; ++kc) {
    us8 bh = *(const us8*)&Hl[(16 * w + l15) * 136 + kc * 32 + g * 8];
    #pragma unroll
    for (int mb = 0; mb < 4; ++mb) {
      us8 a2 = *(const us8*)(W2F + (size_t)((kc * 4 + mb) * 64 + l) * 8);
      c2[mb] = mfma16(a2, bh, c2[mb]);
    }
  }

  if (MODE == 1) {
    size_t e = e0 + 16 * w + l15;
    #pragma unroll
    for (int mb = 0; mb < 4; ++mb)
      *(uint2*)((unsigned short*)outv + e * 64 + 16 * mb + 4 * g) =
          pack4(c2[mb][0], c2[mb][1], c2[mb][2], c2[mb][3]);
  } else {
    #pragma unroll
    for (int mb = 0; mb < 4; ++mb)
      *(float4*)((float*)outv + (size_t)orig * 64 + 16 * mb + 4 * g) =
          (float4){c2[mb][0], c2[mb][1], c2[mb][2], c2[mb][3]};
  }
}

// ---------------------------------------------------------------------------
// Node GEMM, K=128, optional per-block column-stat partials (NO atomics).
// MODE 0: U = [in0(f32,64)|in1(f32,64)]. MODE 1: U = relu(in0*sc+bi), in0 bf16[128].
template<int MODE, int OUTW, bool OUTBF, bool STATS>
__global__ __launch_bounds__(256) void node_mfma(
    const void* __restrict__ in0v, const float* __restrict__ in1,
    const float* __restrict__ sc, const float* __restrict__ bi,
    const unsigned short* __restrict__ WT, const float* __restrict__ B,
    void* __restrict__ yv, float* __restrict__ part) {
  __shared__ __align__(16) unsigned short Ul[64 * 136];
  const int t = threadIdx.x;
  const int w = t >> 6, l = t & 63, g = l >> 4, l15 = l & 15;
  const int r0 = blockIdx.x * 64;
  constexpr int NMB = OUTW / 64;

  {
    int r = t >> 2, q = t & 3;
    int row = r0 + r;
    int rr = row < NN ? row : NN - 1;
    unsigned short tmp[32];
    if (MODE == 0) {
      const float* base = (q < 2) ? (const float*)in0v : in1;
      const float4* p = (const float4*)(base + (size_t)rr * 64 + (q & 1) * 32);
      #pragma unroll
      for (int i = 0; i < 8; ++i) {
        float4 v = p[i];
        tmp[4*i+0] = f2bf(v.x); tmp[4*i+1] = f2bf(v.y);
        tmp[4*i+2] = f2bf(v.z); tmp[4*i+3] = f2bf(v.w);
      }
    } else {
      const unsigned short* srcp = (const unsigned short*)in0v + (size_t)rr * 128 + q * 32;
      #pragma unroll
      for (int i = 0; i < 4; ++i) {
        uint4 u = *(const uint4*)(srcp + i * 8);
        const unsigned short* us = (const unsigned short*)&u;
        #pragma unroll
        for (int j2 = 0; j2 < 2; ++j2) {
          int cb = q * 32 + i * 8 + j2 * 4;
          float4 s = *(const float4*)(sc + cb);
          float4 b = *(const float4*)(bi + cb);
          tmp[i*8+j2*4+0] = f2bf(fmaxf(bf2f(us[j2*4+0]) * s.x + b.x, 0.f));
          tmp[i*8+j2*4+1] = f2bf(fmaxf(bf2f(us[j2*4+1]) * s.y + b.y, 0.f));
          tmp[i*8+j2*4+2] = f2bf(fmaxf(bf2f(us[j2*4+2]) * s.z + b.z, 0.f));
          tmp[i*8+j2*4+3] = f2bf(fmaxf(bf2f(us[j2*4+3]) * s.w + b.w, 0.f));
        }
      }
    }
    unsigned short* ur = &Ul[r * 136 + q * 32];
    #pragma unroll
    for (int i = 0; i < 4; ++i)
      *(uint4*)&ur[i * 8] = *(uint4*)(tmp + i * 8);
  }

  __syncthreads();

  f4 c[NMB][4];
  #pragma unroll
  for (int mm = 0; mm < NMB; ++mm) {
    float4 bb = *(const float4*)(B + 16 * (NMB * w + mm) + 4 * g);
    #pragma unroll
    for (int nb = 0; nb < 4; ++nb)
      c[mm][nb] = (f4){bb.x, bb.y, bb.z, bb.w};
  }

  #pragma unroll
  for (int kc = 0; kc < 4; ++kc) {
    us8 bu[4];
    #pragma unroll
    for (int nb = 0; nb < 4; ++nb)
      bu[nb] = *(const us8*)&Ul[(16 * nb + l15) * 136 + kc * 32 + g * 8];
    #pragma unroll
    for (int mm = 0; mm < NMB; ++mm) {
      us8 a = *(const us8*)(WT + (size_t)(16 * (NMB * w + mm) + l15) * 128
                            + kc * 32 + g * 8);
      #pragma unroll
      for (int nb = 0; nb < 4; ++nb)
        c[mm][nb] = mfma16(a, bu[nb], c[mm][nb]);
    }
  }

  #pragma unroll
  for (int mm = 0; mm < NMB; ++mm)
    #pragma unroll
    for (int nb = 0; nb < 4; ++nb) {
      int row = r0 + l15 + 16 * nb;
      if (row < NN) {
        int f0 = 16 * (NMB * w + mm) + 4 * g;
        if (OUTBF) {
          *(uint2*)((unsigned short*)yv + (size_t)row * OUTW + f0) =
              pack4(c[mm][nb][0], c[mm][nb][1], c[mm][nb][2], c[mm][nb][3]);
        } else {
          *(float4*)((float*)yv + (size_t)row * OUTW + f0) =
              (float4){c[mm][nb][0], c[mm][nb][1], c[mm][nb][2], c[mm][nb][3]};
        }
      }
    }

  if (STATS) {
    float msk[4];
    #pragma unroll
    for (int nb = 0; nb < 4; ++nb)
      msk[nb] = (r0 + 16 * nb + l15 < NN) ? 1.f : 0.f;
    #pragma unroll
    for (int mm = 0; mm < NMB; ++mm) {
      float sv[4], qv[4];
      #pragma unroll
      for (int r = 0; r < 4; ++r) {
        float s = 0.f, q = 0.f;
        #pragma unroll
        for (int nb = 0; nb < 4; ++nb) {
          float v = c[mm][nb][r] * msk[nb];
          s += v; q += v * v;
        }
        #pragma unroll
        for (int d = 1; d < 16; d <<= 1) {
          s += __shfl_xor(s, d);
          q += __shfl_xor(q, d);
        }
        sv[r] = s; qv[r] = q;
      }
      if (l15 == 0) {
        int f0 = 16 * (NMB * w + mm) + 4 * g;
        *(float4*)&part[(size_t)blockIdx.x * 256 + f0] =
            (float4){sv[0], sv[1], sv[2], sv[3]};
        *(float4*)&part[(size_t)blockIdx.x * 256 + 128 + f0] =
            (float4){qv[0], qv[1], qv[2], qv[3]};
      }
    }
  }
}

// ---------------------------------------------------------------------------
// Last node layer (bn(y)->relu -> @h_w4 -> h_out f32) + fused QAB epilogue.
__global__ __launch_bounds__(256) void node_last_qab(
    const unsigned short* __restrict__ in0, const float* __restrict__ sc,
    const float* __restrict__ bi,
    const unsigned short* __restrict__ WT, const float* __restrict__ B,
    const unsigned short* __restrict__ WQ,
    float* __restrict__ hout, unsigned short* __restrict__ QAB) {
  __shared__ __align__(16) unsigned short Ul[64 * 136];
  const int t = threadIdx.x;
  const int w = t >> 6, l = t & 63, g = l >> 4, l15 = l & 15;
  const int r0 = blockIdx.x * 64;

  {
    int r = t >> 2, q = t & 3;
    int row = r0 + r;
    int rr = row < NN ? row : NN - 1;
    unsigned short tmp[32];
    const unsigned short* srcp = in0 + (size_t)rr * 128 + q * 32;
    #pragma unroll
    for (int i = 0; i < 4; ++i) {
      uint4 u = *(const uint4*)(srcp + i * 8);
      const unsigned short* us = (const unsigned short*)&u;
      #pragma unroll
      for (int j2 = 0; j2 < 2; ++j2) {
        int cb = q * 32 + i * 8 + j2 * 4;
        float4 s = *(const float4*)(sc + cb);
        float4 b = *(const float4*)(bi + cb);
        tmp[i*8+j2*4+0] = f2bf(fmaxf(bf2f(us[j2*4+0]) * s.x + b.x, 0.f));
        tmp[i*8+j2*4+1] = f2bf(fmaxf(bf2f(us[j2*4+1]) * s.y + b.y, 0.f));
        tmp[i*8+j2*4+2] = f2bf(fmaxf(bf2f(us[j2*4+2]) * s.z + b.z, 0.f));
        tmp[i*8+j2*4+3] = f2bf(fmaxf(bf2f(us[j2*4+3]) * s.w + b.w, 0.f));
      }
    }
    unsigned short* ur = &Ul[r * 136 + q * 32];
    #pragma unroll
    for (int i = 0; i < 4; ++i)
      *(uint4*)&ur[i * 8] = *(uint4*)(tmp + i * 8);
  }

  __syncthreads();

  f4 c[4];
  {
    float4 bb = *(const float4*)(B + 16 * w + 4 * g);
    #pragma unroll
    for (int nb = 0; nb < 4; ++nb)
      c[nb] = (f4){bb.x, bb.y, bb.z, bb.w};
  }
  #pragma unroll
  for (int kc = 0; kc < 4; ++kc) {
    us8 bu[4];
    #pragma unroll
    for (int nb = 0; nb < 4; ++nb)
      bu[nb] = *(const us8*)&Ul[(16 * nb + l15) * 136 + kc * 32 + g * 8];
    us8 a = *(const us8*)(WT + (size_t)(16 * w + l15) * 128 + kc * 32 + g * 8);
    #pragma unroll
    for (int nb = 0; nb < 4; ++nb)
      c[nb] = mfma16(a, bu[nb], c[nb]);
  }

  #pragma unroll
  for (int nb = 0; nb < 4; ++nb) {
    int row = r0 + l15 + 16 * nb;
    if (row < NN) {
      int f0 = 16 * w + 4 * g;
      *(float4*)(hout + (size_t)row * 64 + f0) =
          (float4){c[nb][0], c[nb][1], c[nb][2], c[nb][3]};
    }
  }

  // ---- QAB epilogue: relu(h_out) @ WQ^T, swizzled out
  __syncthreads();   // everyone done reading Ul
  #pragma unroll
  for (int nb = 0; nb < 4; ++nb) {
    *(uint2*)&Ul[(16 * nb + l15) * 72 + 16 * w + 4 * g] =
        pack4(fmaxf(c[nb][0], 0.f), fmaxf(c[nb][1], 0.f),
              fmaxf(c[nb][2], 0.f), fmaxf(c[nb][3], 0.f));
  }
  us8 aq[4][2];
  #pragma unroll
  for (int mm = 0; mm < 4; ++mm)
    #pragma unroll
    for (int kc = 0; kc < 2; ++kc)
      aq[mm][kc] = *(const us8*)(WQ + (size_t)(64 * w + 16 * mm + l15) * 64 + kc * 32 + g * 8);
  __syncthreads();

  f4 cq[4][4];
  #pragma unroll
  for (int mm = 0; mm < 4; ++mm)
    #pragma unroll
    for (int nb = 0; nb < 4; ++nb)
      cq[mm][nb] = (f4){0.f, 0.f, 0.f, 0.f};
  #pragma unroll
  for (int kc = 0; kc < 2; ++kc) {
    us8 bz[4];
    #pragma unroll
    for (int nb = 0; nb < 4; ++nb)
      bz[nb] = *(const us8*)&Ul[(16 * nb + l15) * 72 + kc * 32 + g * 8];
    #pragma unroll
    for (int mm = 0; mm < 4; ++mm)
      #pragma unroll
      for (int nb = 0; nb < 4; ++nb)
        cq[mm][nb] = mfma16(aq[mm][kc], bz[nb], cq[mm][nb]);
  }
  #pragma unroll
  for (int mm = 0; mm < 4; ++mm)
    #pragma unroll
    for (int nb = 0; nb < 4; ++nb) {
      int row = r0 + 16 * nb + l15;
      if (row < NN) {
        int f0 = 64 * w + 16 * mm + 4 * g;
        int half = f0 >> 7;
        int f1 = f0 & 127;
        int pos = half * 128 + ((f1 >> 5) << 5) + (((f1 & 15) >> 2) << 3) + (((f1 >> 4) & 1) << 2);
        *(uint2*)(QAB + (size_t)row * 256 + pos) =
            pack4(cq[mm][nb][0], cq[mm][nb][1], cq[mm][nb][2], cq[mm][nb][3]);
      }
    }
}

// ---------------------------------------------------------------------------
// Per-node online scatter-softmax over CSR-contiguous m rows (bf16).
// Four independent online states (4 loads in flight), merged at the end.
__global__ void node_softmax(const unsigned short* __restrict__ m,
                             const int* __restrict__ off,
                             const float* __restrict__ tptr,
                             float* __restrict__ msg) {
  int gw = (blockIdx.x * 256 + threadIdx.x) >> 6;
  int lane = threadIdx.x & 63;
  if (gw >= NN) return;
  float t = tptr[0];
  int beg = off[gw], end = off[gw + 1];
  int len = end - beg;
  float M[4] = {-3e38f, -3e38f, -3e38f, -3e38f};
  float S[4] = {0.f, 0.f, 0.f, 0.f};
  float W[4] = {0.f, 0.f, 0.f, 0.f};
  int i = beg;
  for (; i + 3 < end; i += 4) {
    float v0 = bf2f(m[(size_t)(i + 0) * 64 + lane]);
    float v1 = bf2f(m[(size_t)(i + 1) * 64 + lane]);
    float v2 = bf2f(m[(size_t)(i + 2) * 64 + lane]);
    float v3 = bf2f(m[(size_t)(i + 3) * 64 + lane]);
    float s0 = v0 * t, s1 = v1 * t, s2 = v2 * t, s3 = v3 * t;
    float M0 = fmaxf(M[0], s0), M1 = fmaxf(M[1], s1);
    float M2 = fmaxf(M[2], s2), M3 = fmaxf(M[3], s3);
    float c0 = __expf(M[0] - M0), c1 = __expf(M[1] - M1);
    float c2 = __expf(M[2] - M2), c3 = __expf(M[3] - M3);
    float p0 = __expf(s0 - M0), p1 = __expf(s1 - M1);
    float p2 = __expf(s2 - M2), p3 = __expf(s3 - M3);
    S[0] = S[0] * c0 + p0;  W[0] = W[0] * c0 + v0 * p0;  M[0] = M0;
    S[1] = S[1] * c1 + p1;  W[1] = W[1] * c1 + v1 * p1;  M[1] = M1;
    S[2] = S[2] * c2 + p2;  W[2] = W[2] * c2 + v2 * p2;  M[2] = M2;
    S[3] = S[3] * c3 + p3;  W[3] = W[3] * c3 + v3 * p3;  M[3] = M3;
  }
  for (; i < end; ++i) {
    float v0 = bf2f(m[(size_t)i * 64 + lane]);
    float s0 = v0 * t;
    float M0 = fmaxf(M[0], s0);
    float c0 = __expf(M[0] - M0);
    float p0 = __expf(s0 - M0);
    S[0] = S[0] * c0 + p0;  W[0] = W[0] * c0 + v0 * p0;  M[0] = M0;
  }
  float Mn = fmaxf(fmaxf(M[0], M[1]), fmaxf(M[2], M[3]));
  float Sm = 0.f, Wm = 0.f;
  #pragma unroll
  for (int k = 0; k < 4; ++k) {
    float ck = __expf(M[k] - Mn);
    Sm += S[k] * ck;
    Wm += W[k] * ck;
  }
  msg[(size_t)gw * 64 + lane] = (len > 0) ? (Wm / Sm) : 0.f;
}

// ---------------------------------------------------------------------------
extern "C" void kernel_launch(void* const* d_in, const int* in_sizes, int n_in,
                              void* d_out, int out_size, void* d_ws, size_t ws_size,
                              hipStream_t stream) {
  const float* x     = (const float*)d_in[0];
  const int*   ei    = (const int*)d_in[1];
  const float* ea    = (const float*)d_in[2];
  const float* gh_w  = (const float*)d_in[3];
  const float* gh_b  = (const float*)d_in[4];
  const float* gv_w  = (const float*)d_in[5];
  const float* gv_b  = (const float*)d_in[6];
  const float* tpar  = (const float*)d_in[7];
  const float* p_w1  = (const float*)d_in[8];
  const float* p_b1  = (const float*)d_in[9];
  const float* p_w2  = (const float*)d_in[10];
  const float* p_b2  = (const float*)d_in[11];
  const float* h_w1  = (const float*)d_in[12];
  const float* h_b1  = (const float*)d_in[13];
  const float* h_g1  = (const float*)d_in[14];
  const float* h_bb1 = (const float*)d_in[15];
  const float* h_w2  = (const float*)d_in[16];
  const float* h_b2  = (const float*)d_in[17];
  const float* h_g2  = (const float*)d_in[18];
  const float* h_bb2 = (const float*)d_in[19];
  const float* h_w3  = (const float*)d_in[20];
  const float* h_b3  = (const float*)d_in[21];
  const float* h_g3  = (const float*)d_in[22];
  const float* h_bb3 = (const float*)d_in[23];
  const float* h_w4  = (const float*)d_in[24];
  const float* h_b4  = (const float*)d_in[25];
  const float* e_w1  = (const float*)d_in[26];
  const float* e_b1  = (const float*)d_in[27];
  const float* e_w2  = (const float*)d_in[28];
  const float* e_b2  = (const float*)d_in[29];

  float* h_out = (float*)d_out;
  float* v_out = (float*)d_out + (size_t)NN * 64;

  const int* src = ei;
  const int* dst = ei + NE;

  char* w = (char*)d_ws;
  int* cnt = (int*)w;                       // 200704 B, zeroed
  size_t zero_bytes = 200704;

  char* p = w + zero_bytes;
  float* sb = (float*)p; p += 4096;
  float* sbx_s = sb,       *sbx_b = sb + 64;
  float* sbv_s = sb + 128, *sbv_b = sb + 192;
  float* sb1_s = sb + 256, *sb1_b = sb + 384;
  float* sb2_s = sb + 512, *sb2_b = sb + 640;
  float* sb3_s = sb + 768, *sb3_b = sb + 896;
  float* pstat = (float*)p; p += 1280 * 128 * 4;
  float* npart = (float*)p; p += 782 * 256 * 4;
  int* bsum   = (int*)p; p += 1024;
  int* off    = (int*)p; p += 200704;
  int* rank   = (int*)p; p += (size_t)NE * 4;
  int* einv   = (int*)p; p += (size_t)NE * 4;
  int* src_s  = (int*)p; p += (size_t)NE * 4;
  int* dst_s  = (int*)p; p += (size_t)NE * 4;
  float* h    = (float*)p; p += (size_t)NN * 64 * 4;
  float* msg  = (float*)p; p += (size_t)NN * 64 * 4;
  unsigned short* vbf  = (unsigned short*)p; p += (size_t)NE * 64 * 2;
  unsigned short* m_bf = (unsigned short*)p; p += (size_t)NE * 64 * 2;
  unsigned short* PAB  = (unsigned short*)p; p += (size_t)NN * 256 * 2;
  unsigned short* QAB  = (unsigned short*)p; p += (size_t)NN * 256 * 2;
  unsigned short* y1   = (unsigned short*)p; p += (size_t)NN * 128 * 2;
  unsigned short* y2   = (unsigned short*)p; p += (size_t)NN * 128 * 2;
  unsigned short* wpab  = (unsigned short*)p; p += 256 * 64 * 2;
  unsigned short* wqab  = (unsigned short*)p; p += 256 * 64 * 2;
  unsigned short* w1c_p = (unsigned short*)p; p += 128 * 64 * 2;
  unsigned short* w1c_e = (unsigned short*)p; p += 128 * 64 * 2;
  unsigned short* w2f_p = (unsigned short*)p; p += 64 * 128 * 2;
  unsigned short* w2f_e = (unsigned short*)p; p += 64 * 128 * 2;
  unsigned short* h_w1t = (unsigned short*)p; p += 128 * 128 * 2;
  unsigned short* h_w2t = (unsigned short*)p; p += 128 * 128 * 2;
  unsigned short* h_w3t = (unsigned short*)p; p += 128 * 128 * 2;
  unsigned short* h_w4t = (unsigned short*)p; p += 64 * 128 * 2;

  hipMemsetAsync(d_ws, 0, zero_bytes, stream);

  wprep<<<480, 256, 0, stream>>>(p_w1, e_w1, p_w2, e_w2, h_w1, h_w2, h_w3, h_w4,
                                 wpab, wqab, w1c_p, w1c_e, w2f_p, w2f_e,
                                 h_w1t, h_w2t, h_w3t, h_w4t);

  // fused: BN stat partials + CSR count/rank (overlapped in one grid)
  prep_all<<<4405, 256, 0, stream>>>(x, ea, dst, pstat, cnt, rank);

  // hierarchical scan
  scan_part<<<196, 256, 0, stream>>>(cnt, bsum);
  scan_top<<<1, 256, 0, stream>>>(bsum);
  scan_add<<<196, 256, 0, stream>>>(cnt, bsum, off);

  reduce_stats<<<2, 1024, 0, stream>>>(pstat, gh_w, gh_b, gv_w, gv_b, sb);

  // CSR pass 2: atomic-free placement + fused BN scatter of edge_attr
  scatter_all<<<3125, 256, 0, stream>>>(ea, sbv_s, sbv_b, src, dst, off, rank,
                                        src_s, dst_s, einv, vbf);

  // node-side factor: PAB = relu(bn(x)) @ [pW1a|pW1b]; also writes h
  pab_gemm<<<782, 256, 0, stream>>>(x, sbx_s, sbx_b, wpab, PAB, h);

  // message MLP (CSR order): table0 = dst (pW1a), table1 = src (pW1b)
  edge_mlp7<1><<<12500, 256, 0, stream>>>(vbf, PAB, dst_s, src_s, einv,
                                          w1c_p, p_b1, w2f_p, p_b2, (void*)m_bf);

  node_softmax<<<12500, 256, 0, stream>>>(m_bf, off, tpar, msg);

  // node MLP chain: per-block stat partials + tiny reduce (no atomics)
  node_mfma<0, 128, true, true><<<782, 256, 0, stream>>>(
      h, msg, nullptr, nullptr, h_w1t, h_b1, (void*)y1, npart);
  reduce_sb<<<1, 1024, 0, stream>>>(npart, h_g1, h_bb1, sb1_s, sb1_b);

  node_mfma<1, 128, true, true><<<782, 256, 0, stream>>>(
      y1, nullptr, sb1_s, sb1_b, h_w2t, h_b2, (void*)y2, npart);
  reduce_sb<<<1, 1024, 0, stream>>>(npart, h_g2, h_bb2, sb2_s, sb2_b);

  node_mfma<1, 128, true, true><<<782, 256, 0, stream>>>(
      y2, nullptr, sb2_s, sb2_b, h_w3t, h_b3, (void*)y1, npart);
  reduce_sb<<<1, 1024, 0, stream>>>(npart, h_g3, h_bb3, sb3_s, sb3_b);

  // last layer + fused QAB = relu(h_out) @ [eW1a|eW1b]
  node_last_qab<<<782, 256, 0, stream>>>(y1, sb3_s, sb3_b, h_w4t, h_b4, wqab,
                                         h_out, QAB);

  // edge output MLP (CSR order): table0 = src (eW1a), table1 = dst (eW1b)
  edge_mlp7<2><<<12500, 256, 0, stream>>>(vbf, QAB, src_s, dst_s, einv,
                                          w1c_e, e_b1, w2f_e, e_b2, (void*)v_out);
}

// Round 14
// 701.371 us; speedup vs baseline: 1.2899x; 1.0490x over previous
//
#include <hip/hip_runtime.h>
#include <math.h>

#define NN 50000
#define NE 800000

typedef __attribute__((ext_vector_type(8))) unsigned short us8;
typedef __attribute__((ext_vector_type(8))) __bf16 bf8;
typedef __attribute__((ext_vector_type(4))) float f4;

__device__ __forceinline__ unsigned short f2bf(float f) {
  unsigned int u = __float_as_uint(f);
  unsigned int r = u + 0x7FFFu + ((u >> 16) & 1u);
  return (unsigned short)(r >> 16);
}
__device__ __forceinline__ float bf2f(unsigned short h) {
  return __uint_as_float(((unsigned int)h) << 16);
}
__device__ __forceinline__ f4 mfma16(us8 a, us8 b, f4 c) {
  return __builtin_amdgcn_mfma_f32_16x16x32_bf16(
      __builtin_bit_cast(bf8, a), __builtin_bit_cast(bf8, b), c, 0, 0, 0);
}
__device__ __forceinline__ uint2 pack4(float a, float b, float c, float d) {
  uint2 r;
  r.x = (unsigned)f2bf(a) | ((unsigned)f2bf(b) << 16);
  r.y = (unsigned)f2bf(c) | ((unsigned)f2bf(d) << 16);
  return r;
}

// ---------------------------------------------------------------------------
// Fused prep: blocks [0,256) = x stats, [256,1280) = ea stats (per-block
// partials, no atomics), [1280,4405) = CSR count+rank (one atomic pass).
__global__ void prep_all(const float* __restrict__ x, const float* __restrict__ ea,
                         const int* __restrict__ dst,
                         float* __restrict__ pstat, int* __restrict__ cnt,
                         int* __restrict__ rank) {
  int b = blockIdx.x;
  int t = threadIdx.x;
  if (b >= 1280) {                 // count + rank
    int e = (b - 1280) * 256 + t;
    rank[e] = atomicAdd(&cnt[dst[e]], 1);
    return;
  }
  const float* srcp; int rows; int nblk, b0;
  if (b < 256) { srcp = x;  rows = NN; nblk = 256;  b0 = b; }
  else         { srcp = ea; rows = NE; nblk = 1024; b0 = b - 256; }
  int cg = (t & 15) * 4;           // column group (4 cols)
  int rs = t >> 4;                 // row slot 0..15
  float4 s = {0.f, 0.f, 0.f, 0.f}, q = {0.f, 0.f, 0.f, 0.f};
  for (int r = b0 * 64 + rs; r < rows; r += nblk * 64) {
    #pragma unroll
    for (int u = 0; u < 4; ++u) {
      int rr = r + u * 16;
      if (rr < rows) {
        float4 v = *(const float4*)(srcp + (size_t)rr * 64 + cg);
        s.x += v.x; s.y += v.y; s.z += v.z; s.w += v.w;
        q.x += v.x * v.x; q.y += v.y * v.y; q.z += v.z * v.z; q.w += v.w * v.w;
      }
    }
  }
  __shared__ float4 ls[256], lq[256];
  ls[t] = s; lq[t] = q;
  __syncthreads();
  if (rs == 0) {
    #pragma unroll
    for (int i = 1; i < 16; ++i) {
      float4 a = ls[i * 16 + t], z = lq[i * 16 + t];
      s.x += a.x; s.y += a.y; s.z += a.z; s.w += a.w;
      q.x += z.x; q.y += z.y; q.z += z.z; q.w += z.w;
    }
    *(float4*)&pstat[(size_t)b * 128 + cg] = s;
    *(float4*)&pstat[(size_t)b * 128 + 64 + cg] = q;
  }
}

// BN stats pass 2: reduce partials -> scale/bias. block 0 = x, block 1 = ea.
__global__ void reduce_stats(const float* __restrict__ pstat,
                             const float* __restrict__ gh_w, const float* __restrict__ gh_b,
                             const float* __restrict__ gv_w, const float* __restrict__ gv_b,
                             float* __restrict__ sb) {
  int t = threadIdx.x;             // 1024
  int col = t & 63, slot = t >> 6; // 16 slots
  int base = blockIdx.x ? 256 : 0;
  int n = blockIdx.x ? 1024 : 256;
  float s = 0.f, q = 0.f;
  for (int r = slot; r < n; r += 16) {
    s += pstat[(size_t)(base + r) * 128 + col];
    q += pstat[(size_t)(base + r) * 128 + 64 + col];
  }
  __shared__ float ls[1024], lq[1024];
  ls[t] = s; lq[t] = q;
  __syncthreads();
  if (slot == 0) {
    #pragma unroll
    for (int i = 1; i < 16; ++i) { s += ls[i * 64 + col]; q += lq[i * 64 + col]; }
    float inv = blockIdx.x ? (1.0f / NE) : (1.0f / NN);
    const float* gp = blockIdx.x ? gv_w : gh_w;
    const float* bp = blockIdx.x ? gv_b : gh_b;
    float mu = s * inv;
    float var = q * inv - mu * mu;
    float sc = gp[col] * rsqrtf(var + 1e-5f);
    int o = blockIdx.x ? 128 : 0;
    sb[o + col] = sc;
    sb[o + 64 + col] = bp[col] - mu * sc;
  }
}

// Node-layer BN: reduce per-block partials (782 x 256) -> scale/bias (128 cols)
__global__ void reduce_sb(const float* __restrict__ part,
                          const float* __restrict__ g, const float* __restrict__ b,
                          float* __restrict__ scale, float* __restrict__ bias) {
  int t = threadIdx.x;             // 1024
  int col = t & 127, slot = t >> 7; // 8 slots
  float s = 0.f, q = 0.f;
  for (int r = slot; r < 782; r += 8) {
    s += part[(size_t)r * 256 + col];
    q += part[(size_t)r * 256 + 128 + col];
  }
  __shared__ float ls[1024], lq[1024];
  ls[t] = s; lq[t] = q;
  __syncthreads();
  if (slot == 0) {
    #pragma unroll
    for (int i = 1; i < 8; ++i) { s += ls[i * 128 + col]; q += lq[i * 128 + col]; }
    float mu = s * (1.0f / NN);
    float var = q * (1.0f / NN) - mu * mu;
    float sc = g[col] * rsqrtf(var + 1e-5f);
    scale[col] = sc;
    bias[col] = b[col] - mu * sc;
  }
}

// ---------------------------------------------------------------------------
// Fused weight prep.
__global__ void wprep(const float* __restrict__ p_w1, const float* __restrict__ e_w1,
                      const float* __restrict__ p_w2, const float* __restrict__ e_w2,
                      const float* __restrict__ h_w1, const float* __restrict__ h_w2,
                      const float* __restrict__ h_w3, const float* __restrict__ h_w4,
                      unsigned short* __restrict__ wpab, unsigned short* __restrict__ wqab,
                      unsigned short* __restrict__ w1c_p, unsigned short* __restrict__ w1c_e,
                      unsigned short* __restrict__ w2f_p, unsigned short* __restrict__ w2f_e,
                      unsigned short* __restrict__ hw1t, unsigned short* __restrict__ hw2t,
                      unsigned short* __restrict__ hw3t, unsigned short* __restrict__ hw4t) {
  int gi = blockIdx.x * 256 + threadIdx.x;
  if (gi < 32768) {                        // wpab / wqab [256][64]
    const float* w = (gi < 16384) ? p_w1 : e_w1;
    unsigned short* o = (gi < 16384) ? wpab : wqab;
    int i = gi & 16383;
    int f = i >> 6, k = i & 63;
    int srcrow = k + ((f >> 7) << 6);
    o[i] = f2bf(w[(size_t)srcrow * 128 + (f & 127)]);
  } else if (gi < 49152) {                 // w1c_p / w1c_e [128][64]
    int i = (gi - 32768) & 8191;
    const float* w = (gi < 40960) ? (p_w1 + 128 * 128) : (e_w1 + 128 * 128);
    unsigned short* o = (gi < 40960) ? w1c_p : w1c_e;
    int f = i >> 6, k = i & 63;
    o[i] = f2bf(w[(size_t)k * 128 + f]);
  } else if (gi < 65536) {                 // w2f fragment-linear [kc][mb][lane][8]
    int i = (gi - 49152) & 8191;
    const float* w = (gi < 57344) ? p_w2 : e_w2;
    unsigned short* o = (gi < 57344) ? w2f_p : w2f_e;
    int j = i & 7, lane = (i >> 3) & 63, frag = i >> 9;
    int kc = frag >> 2, mb = frag & 3;
    int l15 = lane & 15, g = lane >> 4;
    o[i] = f2bf(w[(size_t)(kc * 32 + g * 8 + j) * 64 + 16 * mb + l15]);
  } else if (gi < 114688) {                // hw1t/hw2t/hw3t [128][128]
    int seg = (gi - 65536) >> 14;
    int i = (gi - 65536) & 16383;
    const float* w = (seg == 0) ? h_w1 : (seg == 1) ? h_w2 : h_w3;
    unsigned short* o = (seg == 0) ? hw1t : (seg == 1) ? hw2t : hw3t;
    int n = i >> 7, k = i & 127;
    o[i] = f2bf(w[(size_t)k * 128 + n]);
  } else if (gi < 122880) {                // hw4t [64][128]
    int i = gi - 114688;
    int n = i >> 7, k = i & 127;
    hw4t[i] = f2bf(h_w4[(size_t)k * 64 + n]);
  }
}

// ---------------------------------------------------------------------------
// hierarchical scan
__global__ void scan_part(const int* __restrict__ cnt, int* __restrict__ bsum) {
  __shared__ int ls[256];
  int i = blockIdx.x * 256 + threadIdx.x;
  ls[threadIdx.x] = (i < NN) ? cnt[i] : 0;
  __syncthreads();
  for (int d = 128; d > 0; d >>= 1) {
    if (threadIdx.x < d) ls[threadIdx.x] += ls[threadIdx.x + d];
    __syncthreads();
  }
  if (threadIdx.x == 0) bsum[blockIdx.x] = ls[0];
}

__global__ void scan_top(int* __restrict__ bsum) {
  __shared__ int ps[256];
  int t = threadIdx.x;
  int v = (t < 196) ? bsum[t] : 0;
  ps[t] = v;
  __syncthreads();
  for (int d = 1; d < 256; d <<= 1) {
    int tv = (t >= d) ? ps[t - d] : 0;
    __syncthreads();
    ps[t] += tv;
    __syncthreads();
  }
  if (t < 196) bsum[t] = ps[t] - v;   // exclusive
}

__global__ void scan_add(const int* __restrict__ cnt, const int* __restrict__ bsum,
                         int* __restrict__ off) {
  __shared__ int ps[256];
  int t = threadIdx.x;
  int i = blockIdx.x * 256 + t;
  int v = (i < NN) ? cnt[i] : 0;
  ps[t] = v;
  __syncthreads();
  for (int d = 1; d < 256; d <<= 1) {
    int tv = (t >= d) ? ps[t - d] : 0;
    __syncthreads();
    ps[t] += tv;
    __syncthreads();
  }
  if (i < NN) off[i] = bsum[blockIdx.x] + ps[t] - v;
  if (blockIdx.x == 0 && t == 0) off[NN] = NE;
}

// ---------------------------------------------------------------------------
// CSR pass 2: placement via off[dst]+rank (NO atomics) + fused BN scatter.
__global__ void scatter_all(const float* __restrict__ ea, const float* __restrict__ sc,
                            const float* __restrict__ bi,
                            const int* __restrict__ srca, const int* __restrict__ dsta,
                            const int* __restrict__ off, const int* __restrict__ rank,
                            int* __restrict__ src_s, int* __restrict__ dst_s,
                            int* __restrict__ einv, unsigned short* __restrict__ vbf) {
  __shared__ int posl[256];
  int t = threadIdx.x;
  int e0 = blockIdx.x * 256;
  int e = e0 + t;
  int n = dsta[e];
  int pos = off[n] + rank[e];
  posl[t] = pos;
  src_s[pos] = srca[e];
  dst_s[pos] = n;
  einv[pos] = e;
  __syncthreads();
  #pragma unroll
  for (int it = 0; it < 8; ++it) {
    int task = it * 256 + t;
    int r = task >> 3, q = task & 7;
    int c8 = q * 8;
    const float4* px = (const float4*)(ea + (size_t)(e0 + r) * 64 + c8);
    float4 a = px[0], b2 = px[1];
    float4 s0 = *(const float4*)(sc + c8), s1 = *(const float4*)(sc + c8 + 4);
    float4 b0 = *(const float4*)(bi + c8),  b1 = *(const float4*)(bi + c8 + 4);
    unsigned short tmp[8];
    tmp[0] = f2bf(fmaxf(a.x * s0.x + b0.x, 0.f));
    tmp[1] = f2bf(fmaxf(a.y * s0.y + b0.y, 0.f));
    tmp[2] = f2bf(fmaxf(a.z * s0.z + b0.z, 0.f));
    tmp[3] = f2bf(fmaxf(a.w * s0.w + b0.w, 0.f));
    tmp[4] = f2bf(fmaxf(b2.x * s1.x + b1.x, 0.f));
    tmp[5] = f2bf(fmaxf(b2.y * s1.y + b1.y, 0.f));
    tmp[6] = f2bf(fmaxf(b2.z * s1.z + b1.z, 0.f));
    tmp[7] = f2bf(fmaxf(b2.w * s1.w + b1.w, 0.f));
    *(uint4*)(vbf + (size_t)posl[r] * 64 + c8) = *(uint4*)tmp;
  }
}

// ---------------------------------------------------------------------------
// PAB = bf16( relu(bn(in)) @ WT^T ), gather-swizzled out; also writes h (f32).
__global__ __launch_bounds__(256) void pab_gemm(
    const float* __restrict__ in, const float* __restrict__ sc,
    const float* __restrict__ bi, const unsigned short* __restrict__ WT,
    unsigned short* __restrict__ out, float* __restrict__ hout) {
  __shared__ __align__(16) unsigned short Ul[64 * 72];
  const int t = threadIdx.x;
  const int w = t >> 6, l = t & 63, g = l >> 4, l15 = l & 15;
  const int r0 = blockIdx.x * 64;

  #pragma unroll
  for (int it = 0; it < 2; ++it) {
    int idx = it * 256 + t;
    int r = idx >> 3, q = idx & 7;
    int row = r0 + r; int rr = row < NN ? row : NN - 1;
    float4 v = *(const float4*)(in + (size_t)rr * 64 + q * 8);
    float4 v2 = *(const float4*)(in + (size_t)rr * 64 + q * 8 + 4);
    float4 s0 = *(const float4*)(sc + q * 8), s1 = *(const float4*)(sc + q * 8 + 4);
    float4 c0 = *(const float4*)(bi + q * 8), c1 = *(const float4*)(bi + q * 8 + 4);
    v.x = fmaxf(v.x * s0.x + c0.x, 0.f);   v.y = fmaxf(v.y * s0.y + c0.y, 0.f);
    v.z = fmaxf(v.z * s0.z + c0.z, 0.f);   v.w = fmaxf(v.w * s0.w + c0.w, 0.f);
    v2.x = fmaxf(v2.x * s1.x + c1.x, 0.f); v2.y = fmaxf(v2.y * s1.y + c1.y, 0.f);
    v2.z = fmaxf(v2.z * s1.z + c1.z, 0.f); v2.w = fmaxf(v2.w * s1.w + c1.w, 0.f);
    unsigned short tmp[8];
    tmp[0] = f2bf(v.x);  tmp[1] = f2bf(v.y);  tmp[2] = f2bf(v.z);  tmp[3] = f2bf(v.w);
    tmp[4] = f2bf(v2.x); tmp[5] = f2bf(v2.y); tmp[6] = f2bf(v2.z); tmp[7] = f2bf(v2.w);
    *(uint4*)&Ul[r * 72 + q * 8] = *(uint4*)tmp;
    if (row < NN) {
      *(float4*)(hout + (size_t)row * 64 + q * 8) = v;
      *(float4*)(hout + (size_t)row * 64 + q * 8 + 4) = v2;
    }
  }
  us8 a[4][2];
  #pragma unroll
  for (int mm = 0; mm < 4; ++mm)
    #pragma unroll
    for (int kc = 0; kc < 2; ++kc)
      a[mm][kc] = *(const us8*)(WT + (size_t)(64 * w + 16 * mm + l15) * 64 + kc * 32 + g * 8);
  __syncthreads();

  f4 c[4][4];
  #pragma unroll
  for (int mm = 0; mm < 4; ++mm)
    #pragma unroll
    for (int nb = 0; nb < 4; ++nb)
      c[mm][nb] = (f4){0.f, 0.f, 0.f, 0.f};
  #pragma unroll
  for (int kc = 0; kc < 2; ++kc) {
    us8 bz[4];
    #pragma unroll
    for (int nb = 0; nb < 4; ++nb)
      bz[nb] = *(const us8*)&Ul[(16 * nb + l15) * 72 + kc * 32 + g * 8];
    #pragma unroll
    for (int mm = 0; mm < 4; ++mm)
      #pragma unroll
      for (int nb = 0; nb < 4; ++nb)
        c[mm][nb] = mfma16(a[mm][kc], bz[nb], c[mm][nb]);
  }
  #pragma unroll
  for (int mm = 0; mm < 4; ++mm)
    #pragma unroll
    for (int nb = 0; nb < 4; ++nb) {
      int row = r0 + 16 * nb + l15;
      if (row < NN) {
        int f0 = 64 * w + 16 * mm + 4 * g;
        int half = f0 >> 7;
        int f1 = f0 & 127;
        int pos = half * 128 + ((f1 >> 5) << 5) + (((f1 & 15) >> 2) << 3) + (((f1 >> 4) & 1) << 2);
        *(uint2*)(out + (size_t)row * 256 + pos) =
            pack4(c[mm][nb][0], c[mm][nb][1], c[mm][nb][2], c[mm][nb][3]);
      }
    }
}

// ---------------------------------------------------------------------------
// Edge MLP v8: v4 structure, but wave w owns OUTPUT-FEATURE block w in layer 2,
// so its 4 W2 fragments (16 VGPRs) are preloaded in phase 0 -> layer 2 has no
// memory dependency except LDS. No W2l stage: LDS = Hl only (17.4 KB).
// MODE 1: m (bf16) contiguous out. MODE 2: v_out (f32) scatter via einv.
template<int MODE>
__global__ __launch_bounds__(256, 4) void edge_mlp8(
    const unsigned short* __restrict__ vbf,     // CSR-order rows
    const unsigned short* __restrict__ AB,      // swizzled PAB/QAB
    const int* __restrict__ idx0, const int* __restrict__ idx1,
    const int* __restrict__ einv,
    const unsigned short* __restrict__ W1cT, const float* __restrict__ B1,
    const unsigned short* __restrict__ W2F, const float* __restrict__ B2,
    void* __restrict__ outv) {
  __shared__ __align__(16) unsigned short Hl[64 * 136];
  const int t = threadIdx.x;
  const int w = t >> 6, l = t & 63, g = l >> 4, l15 = l & 15;
  int bid = blockIdx.x;
  {  // bijective XCD-chunked swizzle (nwg=12500, 8 XCDs)
    const int q = 12500 / 8, r = 12500 % 8;
    int x = bid % 8, j = bid / 8;
    bid = (x < r ? x * (q + 1) : r * (q + 1) + (x - r) * q) + j;
  }
  const size_t e0 = (size_t)bid * 64;

  // ---- phase 0: gathers, W1c frags, W2 frags (this wave's feature block),
  //               bias, einv — ALL loads issued before any compute
  uint4 ga0[4], ga1[4];
  #pragma unroll
  for (int nb = 0; nb < 4; ++nb) {
    size_t e = e0 + 16 * nb + l15;
    int n0 = idx0[e], n1 = idx1[e];
    ga0[nb] = *(const uint4*)(AB + (size_t)n0 * 256 + w * 32 + g * 8);
    ga1[nb] = *(const uint4*)(AB + (size_t)n1 * 256 + 128 + w * 32 + g * 8);
  }
  int orig[4];
  if (MODE == 2) {
    #pragma unroll
    for (int nb = 0; nb < 4; ++nb)
      orig[nb] = einv[e0 + 16 * nb + l15];
  }
  us8 a2[4];
  #pragma unroll
  for (int kc = 0; kc < 4; ++kc)
    a2[kc] = *(const us8*)(W2F + (size_t)((kc * 4 + w) * 64 + l) * 8);
  float4 bb2 = *(const float4*)(B2 + 16 * w + 4 * g);
  us8 a1[2][2];
  #pragma unroll
  for (int mm = 0; mm < 2; ++mm)
    #pragma unroll
    for (int kc = 0; kc < 2; ++kc)
      a1[mm][kc] = *(const us8*)(W1cT + (size_t)(32 * w + 16 * mm + l15) * 64
                                 + kc * 32 + g * 8);

  // ---- phase 1: layer 1 MFMA, V directly from global (rows contiguous)
  f4 c1[2][4];
  #pragma unroll
  for (int mm = 0; mm < 2; ++mm)
    #pragma unroll
    for (int nb = 0; nb < 4; ++nb)
      c1[mm][nb] = (f4){0.f, 0.f, 0.f, 0.f};
  #pragma unroll
  for (int kc = 0; kc < 2; ++kc) {
    us8 bz[4];
    #pragma unroll
    for (int nb = 0; nb < 4; ++nb)
      bz[nb] = *(const us8*)(vbf + (e0 + 16 * nb + l15) * 64 + kc * 32 + g * 8);
    #pragma unroll
    for (int mm = 0; mm < 2; ++mm)
      #pragma unroll
      for (int nb = 0; nb < 4; ++nb)
        c1[mm][nb] = mfma16(a1[mm][kc], bz[nb], c1[mm][nb]);
  }

  // ---- phase 2: H = relu(c1 + B1 + ga0 + ga1) -> Hl (bf16)
  #pragma unroll
  for (int mm = 0; mm < 2; ++mm) {
    float4 bb = *(const float4*)(B1 + 32 * w + 16 * mm + 4 * g);
    #pragma unroll
    for (int nb = 0; nb < 4; ++nb) {
      f4 v = c1[mm][nb];
      unsigned int ux = mm ? ga0[nb].z : ga0[nb].x;
      unsigned int uy = mm ? ga0[nb].w : ga0[nb].y;
      unsigned int vx = mm ? ga1[nb].z : ga1[nb].x;
      unsigned int vy = mm ? ga1[nb].w : ga1[nb].y;
      float h0 = v[0] + bb.x + bf2f((unsigned short)(ux & 0xffff))
                             + bf2f((unsigned short)(vx & 0xffff));
      float h1 = v[1] + bb.y + bf2f((unsigned short)(ux >> 16))
                             + bf2f((unsigned short)(vx >> 16));
      float h2 = v[2] + bb.z + bf2f((unsigned short)(uy & 0xffff))
                             + bf2f((unsigned short)(vy & 0xffff));
      float h3 = v[3] + bb.w + bf2f((unsigned short)(uy >> 16))
                             + bf2f((unsigned short)(vy >> 16));
      int er = 16 * nb + l15;
      *(uint2*)&Hl[er * 136 + 32 * w + 16 * mm + 4 * g] =
          pack4(fmaxf(h0, 0.f), fmaxf(h1, 0.f), fmaxf(h2, 0.f), fmaxf(h3, 0.f));
    }
  }
  __syncthreads();   // Hl ready

  // ---- phase 3: layer 2 — wave w computes features [16w,16w+16) for ALL
  //               64 edges; A-operands already in registers (a2).
  f4 c2[4];
  #pragma unroll
  for (int nb = 0; nb < 4; ++nb)
    c2[nb] = (f4){bb2.x, bb2.y, bb2.z, bb2.w};
  #pragma unroll
  for (int kc = 0; kc < 4; ++kc) {
    us8 bh[4];
    #pragma unroll
    for (int nb = 0; nb < 4; ++nb)
      bh[nb] = *(const us8*)&Hl[(16 * nb + l15) * 136 + kc * 32 + g * 8];
    #pragma unroll
    for (int nb = 0; nb < 4; ++nb)
      c2[nb] = mfma16(a2[kc], bh[nb], c2[nb]);
  }

  if (MODE == 1) {
    #pragma unroll
    for (int nb = 0; nb < 4; ++nb) {
      size_t e = e0 + 16 * nb + l15;
      *(uint2*)((unsigned short*)outv + e * 64 + 16 * w + 4 * g) =
          pack4(c2[nb][0], c2[nb][1], c2[nb][2], c2[nb][3]);
    }
  } else {
    #pragma unroll
    for (int nb = 0; nb < 4; ++nb)
      *(float4*)((float*)outv + (size_t)orig[nb] * 64 + 16 * w + 4 * g) =
          (float4){c2[nb][0], c2[nb][1], c2[nb][2], c2[nb][3]};
  }
}

// ---------------------------------------------------------------------------
// Node GEMM, K=128, optional per-block column-stat partials (NO atomics).
// MODE 0: U = [in0(f32,64)|in1(f32,64)]. MODE 1: U = relu(in0*sc+bi), in0 bf16[128].
template<int MODE, int OUTW, bool OUTBF, bool STATS>
__global__ __launch_bounds__(256) void node_mfma(
    const void* __restrict__ in0v, const float* __restrict__ in1,
    const float* __restrict__ sc, const float* __restrict__ bi,
    const unsigned short* __restrict__ WT, const float* __restrict__ B,
    void* __restrict__ yv, float* __restrict__ part) {
  __shared__ __align__(16) unsigned short Ul[64 * 136];
  const int t = threadIdx.x;
  const int w = t >> 6, l = t & 63, g = l >> 4, l15 = l & 15;
  const int r0 = blockIdx.x * 64;
  constexpr int NMB = OUTW / 64;

  {
    int r = t >> 2, q = t & 3;
    int row = r0 + r;
    int rr = row < NN ? row : NN - 1;
    unsigned short tmp[32];
    if (MODE == 0) {
      const float* base = (q < 2) ? (const float*)in0v : in1;
      const float4* p = (const float4*)(base + (size_t)rr * 64 + (q & 1) * 32);
      #pragma unroll
      for (int i = 0; i < 8; ++i) {
        float4 v = p[i];
        tmp[4*i+0] = f2bf(v.x); tmp[4*i+1] = f2bf(v.y);
        tmp[4*i+2] = f2bf(v.z); tmp[4*i+3] = f2bf(v.w);
      }
    } else {
      const unsigned short* srcp = (const unsigned short*)in0v + (size_t)rr * 128 + q * 32;
      #pragma unroll
      for (int i = 0; i < 4; ++i) {
        uint4 u = *(const uint4*)(srcp + i * 8);
        const unsigned short* us = (const unsigned short*)&u;
        #pragma unroll
        for (int j2 = 0; j2 < 2; ++j2) {
          int cb = q * 32 + i * 8 + j2 * 4;
          float4 s = *(const float4*)(sc + cb);
          float4 b = *(const float4*)(bi + cb);
          tmp[i*8+j2*4+0] = f2bf(fmaxf(bf2f(us[j2*4+0]) * s.x + b.x, 0.f));
          tmp[i*8+j2*4+1] = f2bf(fmaxf(bf2f(us[j2*4+1]) * s.y + b.y, 0.f));
          tmp[i*8+j2*4+2] = f2bf(fmaxf(bf2f(us[j2*4+2]) * s.z + b.z, 0.f));
          tmp[i*8+j2*4+3] = f2bf(fmaxf(bf2f(us[j2*4+3]) * s.w + b.w, 0.f));
        }
      }
    }
    unsigned short* ur = &Ul[r * 136 + q * 32];
    #pragma unroll
    for (int i = 0; i < 4; ++i)
      *(uint4*)&ur[i * 8] = *(uint4*)(tmp + i * 8);
  }

  __syncthreads();

  f4 c[NMB][4];
  #pragma unroll
  for (int mm = 0; mm < NMB; ++mm) {
    float4 bb = *(const float4*)(B + 16 * (NMB * w + mm) + 4 * g);
    #pragma unroll
    for (int nb = 0; nb < 4; ++nb)
      c[mm][nb] = (f4){bb.x, bb.y, bb.z, bb.w};
  }

  #pragma unroll
  for (int kc = 0; kc < 4; ++kc) {
    us8 bu[4];
    #pragma unroll
    for (int nb = 0; nb < 4; ++nb)
      bu[nb] = *(const us8*)&Ul[(16 * nb + l15) * 136 + kc * 32 + g * 8];
    #pragma unroll
    for (int mm = 0; mm < NMB; ++mm) {
      us8 a = *(const us8*)(WT + (size_t)(16 * (NMB * w + mm) + l15) * 128
                            + kc * 32 + g * 8);
      #pragma unroll
      for (int nb = 0; nb < 4; ++nb)
        c[mm][nb] = mfma16(a, bu[nb], c[mm][nb]);
    }
  }

  #pragma unroll
  for (int mm = 0; mm < NMB; ++mm)
    #pragma unroll
    for (int nb = 0; nb < 4; ++nb) {
      int row = r0 + l15 + 16 * nb;
      if (row < NN) {
        int f0 = 16 * (NMB * w + mm) + 4 * g;
        if (OUTBF) {
          *(uint2*)((unsigned short*)yv + (size_t)row * OUTW + f0) =
              pack4(c[mm][nb][0], c[mm][nb][1], c[mm][nb][2], c[mm][nb][3]);
        } else {
          *(float4*)((float*)yv + (size_t)row * OUTW + f0) =
              (float4){c[mm][nb][0], c[mm][nb][1], c[mm][nb][2], c[mm][nb][3]};
        }
      }
    }

  if (STATS) {
    float msk[4];
    #pragma unroll
    for (int nb = 0; nb < 4; ++nb)
      msk[nb] = (r0 + 16 * nb + l15 < NN) ? 1.f : 0.f;
    #pragma unroll
    for (int mm = 0; mm < NMB; ++mm) {
      float sv[4], qv[4];
      #pragma unroll
      for (int r = 0; r < 4; ++r) {
        float s = 0.f, q = 0.f;
        #pragma unroll
        for (int nb = 0; nb < 4; ++nb) {
          float v = c[mm][nb][r] * msk[nb];
          s += v; q += v * v;
        }
        #pragma unroll
        for (int d = 1; d < 16; d <<= 1) {
          s += __shfl_xor(s, d);
          q += __shfl_xor(q, d);
        }
        sv[r] = s; qv[r] = q;
      }
      if (l15 == 0) {
        int f0 = 16 * (NMB * w + mm) + 4 * g;
        *(float4*)&part[(size_t)blockIdx.x * 256 + f0] =
            (float4){sv[0], sv[1], sv[2], sv[3]};
        *(float4*)&part[(size_t)blockIdx.x * 256 + 128 + f0] =
            (float4){qv[0], qv[1], qv[2], qv[3]};
      }
    }
  }
}

// ---------------------------------------------------------------------------
// Last node layer (bn(y)->relu -> @h_w4 -> h_out f32) + fused QAB epilogue.
__global__ __launch_bounds__(256) void node_last_qab(
    const unsigned short* __restrict__ in0, const float* __restrict__ sc,
    const float* __restrict__ bi,
    const unsigned short* __restrict__ WT, const float* __restrict__ B,
    const unsigned short* __restrict__ WQ,
    float* __restrict__ hout, unsigned short* __restrict__ QAB) {
  __shared__ __align__(16) unsigned short Ul[64 * 136];
  const int t = threadIdx.x;
  const int w = t >> 6, l = t & 63, g = l >> 4, l15 = l & 15;
  const int r0 = blockIdx.x * 64;

  {
    int r = t >> 2, q = t & 3;
    int row = r0 + r;
    int rr = row < NN ? row : NN - 1;
    unsigned short tmp[32];
    const unsigned short* srcp = in0 + (size_t)rr * 128 + q * 32;
    #pragma unroll
    for (int i = 0; i < 4; ++i) {
      uint4 u = *(const uint4*)(srcp + i * 8);
      const unsigned short* us = (const unsigned short*)&u;
      #pragma unroll
      for (int j2 = 0; j2 < 2; ++j2) {
        int cb = q * 32 + i * 8 + j2 * 4;
        float4 s = *(const float4*)(sc + cb);
        float4 b = *(const float4*)(bi + cb);
        tmp[i*8+j2*4+0] = f2bf(fmaxf(bf2f(us[j2*4+0]) * s.x + b.x, 0.f));
        tmp[i*8+j2*4+1] = f2bf(fmaxf(bf2f(us[j2*4+1]) * s.y + b.y, 0.f));
        tmp[i*8+j2*4+2] = f2bf(fmaxf(bf2f(us[j2*4+2]) * s.z + b.z, 0.f));
        tmp[i*8+j2*4+3] = f2bf(fmaxf(bf2f(us[j2*4+3]) * s.w + b.w, 0.f));
      }
    }
    unsigned short* ur = &Ul[r * 136 + q * 32];
    #pragma unroll
    for (int i = 0; i < 4; ++i)
      *(uint4*)&ur[i * 8] = *(uint4*)(tmp + i * 8);
  }

  __syncthreads();

  f4 c[4];
  {
    float4 bb = *(const float4*)(B + 16 * w + 4 * g);
    #pragma unroll
    for (int nb = 0; nb < 4; ++nb)
      c[nb] = (f4){bb.x, bb.y, bb.z, bb.w};
  }
  #pragma unroll
  for (int kc = 0; kc < 4; ++kc) {
    us8 bu[4];
    #pragma unroll
    for (int nb = 0; nb < 4; ++nb)
      bu[nb] = *(const us8*)&Ul[(16 * nb + l15) * 136 + kc * 32 + g * 8];
    us8 a = *(const us8*)(WT + (size_t)(16 * w + l15) * 128 + kc * 32 + g * 8);
    #pragma unroll
    for (int nb = 0; nb < 4; ++nb)
      c[nb] = mfma16(a, bu[nb], c[nb]);
  }

  #pragma unroll
  for (int nb = 0; nb < 4; ++nb) {
    int row = r0 + l15 + 16 * nb;
    if (row < NN) {
      int f0 = 16 * w + 4 * g;
      *(float4*)(hout + (size_t)row * 64 + f0) =
          (float4){c[nb][0], c[nb][1], c[nb][2], c[nb][3]};
    }
  }

  // ---- QAB epilogue: relu(h_out) @ WQ^T, swizzled out
  __syncthreads();   // everyone done reading Ul
  #pragma unroll
  for (int nb = 0; nb < 4; ++nb) {
    *(uint2*)&Ul[(16 * nb + l15) * 72 + 16 * w + 4 * g] =
        pack4(fmaxf(c[nb][0], 0.f), fmaxf(c[nb][1], 0.f),
              fmaxf(c[nb][2], 0.f), fmaxf(c[nb][3], 0.f));
  }
  us8 aq[4][2];
  #pragma unroll
  for (int mm = 0; mm < 4; ++mm)
    #pragma unroll
    for (int kc = 0; kc < 2; ++kc)
      aq[mm][kc] = *(const us8*)(WQ + (size_t)(64 * w + 16 * mm + l15) * 64 + kc * 32 + g * 8);
  __syncthreads();

  f4 cq[4][4];
  #pragma unroll
  for (int mm = 0; mm < 4; ++mm)
    #pragma unroll
    for (int nb = 0; nb < 4; ++nb)
      cq[mm][nb] = (f4){0.f, 0.f, 0.f, 0.f};
  #pragma unroll
  for (int kc = 0; kc < 2; ++kc) {
    us8 bz[4];
    #pragma unroll
    for (int nb = 0; nb < 4; ++nb)
      bz[nb] = *(const us8*)&Ul[(16 * nb + l15) * 72 + kc * 32 + g * 8];
    #pragma unroll
    for (int mm = 0; mm < 4; ++mm)
      #pragma unroll
      for (int nb = 0; nb < 4; ++nb)
        cq[mm][nb] = mfma16(aq[mm][kc], bz[nb], cq[mm][nb]);
  }
  #pragma unroll
  for (int mm = 0; mm < 4; ++mm)
    #pragma unroll
    for (int nb = 0; nb < 4; ++nb) {
      int row = r0 + 16 * nb + l15;
      if (row < NN) {
        int f0 = 64 * w + 16 * mm + 4 * g;
        int half = f0 >> 7;
        int f1 = f0 & 127;
        int pos = half * 128 + ((f1 >> 5) << 5) + (((f1 & 15) >> 2) << 3) + (((f1 >> 4) & 1) << 2);
        *(uint2*)(QAB + (size_t)row * 256 + pos) =
            pack4(cq[mm][nb][0], cq[mm][nb][1], cq[mm][nb][2], cq[mm][nb][3]);
      }
    }
}

// ---------------------------------------------------------------------------
// Per-node online scatter-softmax over CSR-contiguous m rows (bf16).
// Four independent online states (4 loads in flight), merged at the end.
__global__ void node_softmax(const unsigned short* __restrict__ m,
                             const int* __restrict__ off,
                             const float* __restrict__ tptr,
                             float* __restrict__ msg) {
  int gw = (blockIdx.x * 256 + threadIdx.x) >> 6;
  int lane = threadIdx.x & 63;
  if (gw >= NN) return;
  float t = tptr[0];
  int beg = off[gw], end = off[gw + 1];
  int len = end - beg;
  float M[4] = {-3e38f, -3e38f, -3e38f, -3e38f};
  float S[4] = {0.f, 0.f, 0.f, 0.f};
  float W[4] = {0.f, 0.f, 0.f, 0.f};
  int i = beg;
  for (; i + 3 < end; i += 4) {
    float v0 = bf2f(m[(size_t)(i + 0) * 64 + lane]);
    float v1 = bf2f(m[(size_t)(i + 1) * 64 + lane]);
    float v2 = bf2f(m[(size_t)(i + 2) * 64 + lane]);
    float v3 = bf2f(m[(size_t)(i + 3) * 64 + lane]);
    float s0 = v0 * t, s1 = v1 * t, s2 = v2 * t, s3 = v3 * t;
    float M0 = fmaxf(M[0], s0), M1 = fmaxf(M[1], s1);
    float M2 = fmaxf(M[2], s2), M3 = fmaxf(M[3], s3);
    float c0 = __expf(M[0] - M0), c1 = __expf(M[1] - M1);
    float c2 = __expf(M[2] - M2), c3 = __expf(M[3] - M3);
    float p0 = __expf(s0 - M0), p1 = __expf(s1 - M1);
    float p2 = __expf(s2 - M2), p3 = __expf(s3 - M3);
    S[0] = S[0] * c0 + p0;  W[0] = W[0] * c0 + v0 * p0;  M[0] = M0;
    S[1] = S[1] * c1 + p1;  W[1] = W[1] * c1 + v1 * p1;  M[1] = M1;
    S[2] = S[2] * c2 + p2;  W[2] = W[2] * c2 + v2 * p2;  M[2] = M2;
    S[3] = S[3] * c3 + p3;  W[3] = W[3] * c3 + v3 * p3;  M[3] = M3;
  }
  for (; i < end; ++i) {
    float v0 = bf2f(m[(size_t)i * 64 + lane]);
    float s0 = v0 * t;
    float M0 = fmaxf(M[0], s0);
    float c0 = __expf(M[0] - M0);
    float p0 = __expf(s0 - M0);
    S[0] = S[0] * c0 + p0;  W[0] = W[0] * c0 + v0 * p0;  M[0] = M0;
  }
  float Mn = fmaxf(fmaxf(M[0], M[1]), fmaxf(M[2], M[3]));
  float Sm = 0.f, Wm = 0.f;
  #pragma unroll
  for (int k = 0; k < 4; ++k) {
    float ck = __expf(M[k] - Mn);
    Sm += S[k] * ck;
    Wm += W[k] * ck;
  }
  msg[(size_t)gw * 64 + lane] = (len > 0) ? (Wm / Sm) : 0.f;
}

// ---------------------------------------------------------------------------
extern "C" void kernel_launch(void* const* d_in, const int* in_sizes, int n_in,
                              void* d_out, int out_size, void* d_ws, size_t ws_size,
                              hipStream_t stream) {
  const float* x     = (const float*)d_in[0];
  const int*   ei    = (const int*)d_in[1];
  const float* ea    = (const float*)d_in[2];
  const float* gh_w  = (const float*)d_in[3];
  const float* gh_b  = (const float*)d_in[4];
  const float* gv_w  = (const float*)d_in[5];
  const float* gv_b  = (const float*)d_in[6];
  const float* tpar  = (const float*)d_in[7];
  const float* p_w1  = (const float*)d_in[8];
  const float* p_b1  = (const float*)d_in[9];
  const float* p_w2  = (const float*)d_in[10];
  const float* p_b2  = (const float*)d_in[11];
  const float* h_w1  = (const float*)d_in[12];
  const float* h_b1  = (const float*)d_in[13];
  const float* h_g1  = (const float*)d_in[14];
  const float* h_bb1 = (const float*)d_in[15];
  const float* h_w2  = (const float*)d_in[16];
  const float* h_b2  = (const float*)d_in[17];
  const float* h_g2  = (const float*)d_in[18];
  const float* h_bb2 = (const float*)d_in[19];
  const float* h_w3  = (const float*)d_in[20];
  const float* h_b3  = (const float*)d_in[21];
  const float* h_g3  = (const float*)d_in[22];
  const float* h_bb3 = (const float*)d_in[23];
  const float* h_w4  = (const float*)d_in[24];
  const float* h_b4  = (const float*)d_in[25];
  const float* e_w1  = (const float*)d_in[26];
  const float* e_b1  = (const float*)d_in[27];
  const float* e_w2  = (const float*)d_in[28];
  const float* e_b2  = (const float*)d_in[29];

  float* h_out = (float*)d_out;
  float* v_out = (float*)d_out + (size_t)NN * 64;

  const int* src = ei;
  const int* dst = ei + NE;

  char* w = (char*)d_ws;
  int* cnt = (int*)w;                       // 200704 B, zeroed
  size_t zero_bytes = 200704;

  char* p = w + zero_bytes;
  float* sb = (float*)p; p += 4096;
  float* sbx_s = sb,       *sbx_b = sb + 64;
  float* sbv_s = sb + 128, *sbv_b = sb + 192;
  float* sb1_s = sb + 256, *sb1_b = sb + 384;
  float* sb2_s = sb + 512, *sb2_b = sb + 640;
  float* sb3_s = sb + 768, *sb3_b = sb + 896;
  float* pstat = (float*)p; p += 1280 * 128 * 4;
  float* npart = (float*)p; p += 782 * 256 * 4;
  int* bsum   = (int*)p; p += 1024;
  int* off    = (int*)p; p += 200704;
  int* rank   = (int*)p; p += (size_t)NE * 4;
  int* einv   = (int*)p; p += (size_t)NE * 4;
  int* src_s  = (int*)p; p += (size_t)NE * 4;
  int* dst_s  = (int*)p; p += (size_t)NE * 4;
  float* h    = (float*)p; p += (size_t)NN * 64 * 4;
  float* msg  = (float*)p; p += (size_t)NN * 64 * 4;
  unsigned short* vbf  = (unsigned short*)p; p += (size_t)NE * 64 * 2;
  unsigned short* m_bf = (unsigned short*)p; p += (size_t)NE * 64 * 2;
  unsigned short* PAB  = (unsigned short*)p; p += (size_t)NN * 256 * 2;
  unsigned short* QAB  = (unsigned short*)p; p += (size_t)NN * 256 * 2;
  unsigned short* y1   = (unsigned short*)p; p += (size_t)NN * 128 * 2;
  unsigned short* y2   = (unsigned short*)p; p += (size_t)NN * 128 * 2;
  unsigned short* wpab  = (unsigned short*)p; p += 256 * 64 * 2;
  unsigned short* wqab  = (unsigned short*)p; p += 256 * 64 * 2;
  unsigned short* w1c_p = (unsigned short*)p; p += 128 * 64 * 2;
  unsigned short* w1c_e = (unsigned short*)p; p += 128 * 64 * 2;
  unsigned short* w2f_p = (unsigned short*)p; p += 64 * 128 * 2;
  unsigned short* w2f_e = (unsigned short*)p; p += 64 * 128 * 2;
  unsigned short* h_w1t = (unsigned short*)p; p += 128 * 128 * 2;
  unsigned short* h_w2t = (unsigned short*)p; p += 128 * 128 * 2;
  unsigned short* h_w3t = (unsigned short*)p; p += 128 * 128 * 2;
  unsigned short* h_w4t = (unsigned short*)p; p += 64 * 128 * 2;

  hipMemsetAsync(d_ws, 0, zero_bytes, stream);

  wprep<<<480, 256, 0, stream>>>(p_w1, e_w1, p_w2, e_w2, h_w1, h_w2, h_w3, h_w4,
                                 wpab, wqab, w1c_p, w1c_e, w2f_p, w2f_e,
                                 h_w1t, h_w2t, h_w3t, h_w4t);

  // fused: BN stat partials + CSR count/rank (overlapped in one grid)
  prep_all<<<4405, 256, 0, stream>>>(x, ea, dst, pstat, cnt, rank);

  // hierarchical scan
  scan_part<<<196, 256, 0, stream>>>(cnt, bsum);
  scan_top<<<1, 256, 0, stream>>>(bsum);
  scan_add<<<196, 256, 0, stream>>>(cnt, bsum, off);

  reduce_stats<<<2, 1024, 0, stream>>>(pstat, gh_w, gh_b, gv_w, gv_b, sb);

  // CSR pass 2: atomic-free placement + fused BN scatter of edge_attr
  scatter_all<<<3125, 256, 0, stream>>>(ea, sbv_s, sbv_b, src, dst, off, rank,
                                        src_s, dst_s, einv, vbf);

  // node-side factor: PAB = relu(bn(x)) @ [pW1a|pW1b]; also writes h
  pab_gemm<<<782, 256, 0, stream>>>(x, sbx_s, sbx_b, wpab, PAB, h);

  // message MLP (CSR order): table0 = dst (pW1a), table1 = src (pW1b)
  edge_mlp8<1><<<12500, 256, 0, stream>>>(vbf, PAB, dst_s, src_s, einv,
                                          w1c_p, p_b1, w2f_p, p_b2, (void*)m_bf);

  node_softmax<<<12500, 256, 0, stream>>>(m_bf, off, tpar, msg);

  // node MLP chain: per-block stat partials + tiny reduce (no atomics)
  node_mfma<0, 128, true, true><<<782, 256, 0, stream>>>(
      h, msg, nullptr, nullptr, h_w1t, h_b1, (void*)y1, npart);
  reduce_sb<<<1, 1024, 0, stream>>>(npart, h_g1, h_bb1, sb1_s, sb1_b);

  node_mfma<1, 128, true, true><<<782, 256, 0, stream>>>(
      y1, nullptr, sb1_s, sb1_b, h_w2t, h_b2, (void*)y2, npart);
  reduce_sb<<<1, 1024, 0, stream>>>(npart, h_g2, h_bb2, sb2_s, sb2_b);

  node_mfma<1, 128, true, true><<<782, 256, 0, stream>>>(
      y2, nullptr, sb2_s, sb2_b, h_w3t, h_b3, (void*)y1, npart);
  reduce_sb<<<1, 1024, 0, stream>>>(npart, h_g3, h_bb3, sb3_s, sb3_b);

  // last layer + fused QAB = relu(h_out) @ [eW1a|eW1b]
  node_last_qab<<<782, 256, 0, stream>>>(y1, sb3_s, sb3_b, h_w4t, h_b4, wqab,
                                         h_out, QAB);

  // edge output MLP (CSR order): table0 = src (eW1a), table1 = dst (eW1b)
  edge_mlp8<2><<<12500, 256, 0, stream>>>(vbf, QAB, src_s, dst_s, einv,
                                          w1c_e, e_b1, w2f_e, e_b2, (void*)v_out);
}